// Round 3
// baseline (288.791 us; speedup 1.0000x reference)
//
#include <hip/hip_runtime.h>
#include <cstdint>

typedef unsigned long long u64;
typedef unsigned int u32;

#define WPRE 400
#define MIN_SCORE 0.01f
#define MAX_OVERLAP 0.45f

__device__ __forceinline__ u32 f32_key(float f) {
    u32 u = __float_as_uint(f);
    return (f >= 0.0f) ? (u | 0x80000000u) : ~u;
}
__device__ __forceinline__ float key_f32(u32 k) {
    return __uint_as_float((k & 0x80000000u) ? (k ^ 0x80000000u) : ~k);
}

// Exact K-th selection over 32-bit keys (descending), 4 x 8-bit MSD radix.
// Histogram built with wave-ballot grouping (1 LDS atomic per distinct digit
// per wave) instead of per-key atomics -> no same-address serialization.
template <typename KF>
__device__ void radix_select32(KF kf, int N, int K, int tid, int T,
                               u32* hist, u32* sh_prefix, int* sh_r, int* sh_neq,
                               u32& pivot, int& needed, int& nge)
{
    const int lane = tid & 63;
    if (tid == 0) { *sh_prefix = 0u; *sh_r = K; *sh_neq = 0; }
    __syncthreads();
    for (int d = 3; d >= 0; --d) {
        u32 pref = *sh_prefix;
        int r = *sh_r;
        if (tid < 256) hist[tid] = 0u;
        __syncthreads();
        for (int i = tid; i < N; i += T) {
            u32 k = 0u;
            bool ok = kf(i, k);
            bool match = ok && ((d == 3) || (((k ^ pref) >> ((d + 1) * 8)) == 0u));
            u32 dig = (k >> (d * 8)) & 255u;
            u64 m = __ballot(match);
            #pragma unroll
            for (int bb = 0; bb < 8; ++bb) {
                u64 bm = __ballot((int)((dig >> bb) & 1u));
                m &= ((dig >> bb) & 1u) ? bm : ~bm;
            }
            if (match) {
                u64 lower = m & ((1ull << lane) - 1ull);
                if (lower == 0ull) atomicAdd(&hist[dig], (u32)__builtin_popcountll(m));
            }
        }
        __syncthreads();
        // parallel inclusive suffix sum over 256 bins
        for (int off = 1; off < 256; off <<= 1) {
            u32 vv = 0u;
            if (tid < 256) vv = hist[tid] + ((tid + off < 256) ? hist[tid + off] : 0u);
            __syncthreads();
            if (tid < 256) hist[tid] = vv;
            __syncthreads();
        }
        if (tid < 256) {
            u32 Sv = hist[tid];
            u32 Sn = (tid < 255) ? hist[tid + 1] : 0u;
            if ((int)Sv >= r && (int)Sn < r) {
                *sh_prefix = pref | ((u32)tid << (d * 8));
                *sh_r = r - (int)Sn;
                *sh_neq = (int)(Sv - Sn);
            }
        }
        __syncthreads();
    }
    u32 pv = *sh_prefix; int nd = *sh_r; int ne = *sh_neq;
    __syncthreads();
    pivot = pv; needed = nd; nge = (K - nd) + ne;
}

// ---------------- Kernel 1: decode boxes + softmax (LDS-staged, coalesced) ----------------
__global__ __launch_bounds__(256) void decode_softmax_kernel(
    const float* __restrict__ locs, const float* __restrict__ scores,
    const float* __restrict__ priors, float* __restrict__ dec,
    float* __restrict__ probs_t, int P, int C, int NC)
{
    __shared__ float tile[64 * 81];
    __shared__ float mrow[64], srow[64];
    const int b  = blockIdx.y;
    const int p0 = blockIdx.x * 64;
    const int tid = threadIdx.x;
    const int nrows = min(64, P - p0);
    const int n = nrows * C;

    const float* src = scores + ((size_t)b * P + p0) * C;
    for (int idx = tid; idx < n; idx += 256) tile[idx] = src[idx];

    if (tid < nrows) {
        int p = p0 + tid;
        float4 lc = ((const float4*)locs)[(size_t)b * P + p];
        float4 pr = ((const float4*)priors)[p];
        float cx = lc.x * pr.z / 10.0f + pr.x;
        float cy = lc.y * pr.w / 10.0f + pr.y;
        float w  = expf(lc.z / 5.0f) * pr.z;
        float h  = expf(lc.w / 5.0f) * pr.w;
        ((float4*)dec)[(size_t)b * P + p] =
            make_float4(cx - w * 0.5f, cy - h * 0.5f, cx + w * 0.5f, cy + h * 0.5f);
    }
    __syncthreads();

    if (tid < nrows) {
        const float* row = &tile[tid * C];
        float m = row[0];
        for (int cc = 1; cc < C; ++cc) m = fmaxf(m, row[cc]);
        float ss = 0.f;
        for (int cc = 0; cc < C; ++cc) ss += expf(row[cc] - m);
        mrow[tid] = m; srow[tid] = ss;
    }
    __syncthreads();

    for (int idx = tid; idx < 64 * NC; idx += 256) {
        int r  = idx & 63;
        int cc = idx >> 6;
        if (r < nrows) {
            float v = expf(tile[r * C + cc + 1] - mrow[r]) / srow[r];
            probs_t[((size_t)(b * NC + cc)) * P + p0 + r] = v;
        }
    }
}

// ---------------- Kernel 2: per (class,image) top-400 + NMS ----------------
__global__ __launch_bounds__(512) void nms_kernel(
    const float* __restrict__ dec, const float* __restrict__ probs_t,
    float* __restrict__ cand_sc, float* __restrict__ cand_bx,
    int P, int NC)
{
    const int c = blockIdx.x, b = blockIdx.y;
    const int tid = threadIdx.x;
    const int lane = tid & 63;
    const int wv = tid >> 6;
    const int T = 512;

    // skey (34944 B) is dead after compaction; rowm (400*9*8 = 28800 B) aliases it.
    __shared__ alignas(16) char bufA[8736 * 4];
    u32* skey = (u32*)bufA;
    u64* rowm = (u64*)bufA;
    __shared__ u64 cand[512];
    __shared__ float4 cbox[448];
    __shared__ float ara[448];
    __shared__ u32 hist[256];
    __shared__ u64 validm[7], keepm[7];
    __shared__ u32 sh_prefix;
    __shared__ int sh_r, sh_neq, sh_cnt;

    const float* ps = probs_t + ((size_t)(b * NC + c)) * P;

    // stage masked sortable keys to LDS (vectorized)
    int P4 = P >> 2;
    for (int i = tid; i < P4; i += T) {
        float4 f4 = ((const float4*)ps)[i];
        skey[i*4+0] = f32_key(f4.x > MIN_SCORE ? f4.x : -1.0f);
        skey[i*4+1] = f32_key(f4.y > MIN_SCORE ? f4.y : -1.0f);
        skey[i*4+2] = f32_key(f4.z > MIN_SCORE ? f4.z : -1.0f);
        skey[i*4+3] = f32_key(f4.w > MIN_SCORE ? f4.w : -1.0f);
    }
    for (int i = (P4 << 2) + tid; i < P; i += T) {
        float f = ps[i];
        skey[i] = f32_key(f > MIN_SCORE ? f : -1.0f);
    }
    if (tid == 0) sh_cnt = 0;
    __syncthreads();

    u32 pivot; int needed, nge;
    radix_select32([&](int i, u32& k) { k = skey[i]; return true; },
                   P, WPRE, tid, T, hist, &sh_prefix, &sh_r, &sh_neq,
                   pivot, needed, nge);

    if (nge <= 512) {
        for (int i = tid; i < P; i += T) {
            u32 k = skey[i];
            if (k >= pivot) {
                int pos = atomicAdd(&sh_cnt, 1);
                cand[pos] = ((u64)k << 32) | (u64)(~(u32)i);
            }
        }
    } else {
        // tie flood at pivot: exact secondary select on index key among equals
        u32 pivot2; int needed2, nge2;
        radix_select32([&](int i, u32& k) {
                           if (skey[i] != pivot) return false;
                           k = ~(u32)i; return true;
                       },
                       P, needed, tid, T, hist, &sh_prefix, &sh_r, &sh_neq,
                       pivot2, needed2, nge2);
        for (int i = tid; i < P; i += T) {
            u32 k = skey[i];
            if (k > pivot || (k == pivot && (~(u32)i) >= pivot2)) {
                int pos = atomicAdd(&sh_cnt, 1);
                cand[pos] = ((u64)k << 32) | (u64)(~(u32)i);
            }
        }
    }
    __syncthreads();
    const int cnt = sh_cnt;            // in [400, 512]
    u64 v = (tid < cnt) ? cand[tid] : 0ull;

    // register bitonic sort 512 desc: shfl within wave, LDS only for j>=64
    for (int k = 2; k <= 512; k <<= 1) {
        for (int j = k >> 1; j > 0; j >>= 1) {
            u64 p;
            if (j < 64) {
                p = __shfl_xor(v, j, 64);
            } else {
                __syncthreads();
                cand[tid] = v;
                __syncthreads();
                p = cand[tid ^ j];
            }
            bool takeMax = (((tid & k) == 0) == ((tid & j) == 0));
            v = takeMax ? (v > p ? v : p) : (v > p ? p : v);
        }
    }
    __syncthreads();   // all reads of cand done; skey/rowm region free after this

    // unpack rank-tid candidate (in register) into SoA; slots 400..447 zero-pad
    float4 mybox = make_float4(0.f, 0.f, 0.f, 0.f);
    float myval = -1.0f;
    if (tid < 448) {
        if (tid < WPRE) {
            myval = key_f32((u32)(v >> 32));
            int p = (int)(~(u32)v);
            mybox = ((const float4*)dec)[(size_t)b * P + p];
        }
        cbox[tid] = mybox;
        ara[tid] = (mybox.z - mybox.x) * (mybox.w - mybox.y);
        u64 mk = __ballot(myval > MIN_SCORE);
        if (lane == 0) validm[tid >> 6] = mk;
    }
    __syncthreads();

    // upper-triangle suppression bit-matrix, 64x64 register tiles.
    // tile t -> (r,w), w >= r; lane holds box_j (j = 64w+lane) in registers;
    // per row i: 2 broadcast LDS reads + ballot -> lane (i&63) accumulates word w.
    for (int t = wv; t < 28; t += 8) {
        int r = 0, base = 0;
        while (t - base >= 7 - r) { base += 7 - r; ++r; }
        int w = r + (t - base);
        int nrows = (r == 6) ? (WPRE - 384) : 64;
        int j = (w << 6) + lane;
        float4 bj = cbox[j];
        float aj = ara[j];
        u64 myrow = 0ull;
        #pragma unroll 4
        for (int k2 = 0; k2 < nrows; ++k2) {
            int i = (r << 6) + k2;
            float4 bi = cbox[i];
            float ai = ara[i];
            float lx = fmaxf(bi.x, bj.x);
            float ly = fmaxf(bi.y, bj.y);
            float rx = fminf(bi.z, bj.z);
            float ry = fminf(bi.w, bj.w);
            float ww = fmaxf(rx - lx, 0.f);
            float hh = fmaxf(ry - ly, 0.f);
            float inter = ww * hh;
            float uni = (ai + aj) - inter;
            float q = inter / fmaxf(uni, 1e-10f);
            bool pred = q > MAX_OVERLAP;
            if (w == r && lane == k2) pred = false;    // diagonal
            u64 vote = __ballot(pred);
            if (lane == k2) myrow = vote;
        }
        if (lane < nrows) rowm[(size_t)((r << 6) + lane) * 9 + w] = myrow;
    }
    __syncthreads();

    // serial scan in ONE wave, zero barriers; lower-tri words substituted 0
    if (tid < 64) {
        u64 supw = 0ull;
        u64 valw = (lane < 7) ? validm[lane] : 0ull;
        u64 row_next = (lane < 7) ? rowm[lane] : 0ull;    // i=0
        for (int i = 0; i < WPRE; ++i) {
            u64 row = row_next;
            int inext = i + 1;
            if (inext < WPRE) {
                int wq = inext >> 6;
                row_next = (lane < 7 && lane >= wq) ? rowm[(size_t)inext * 9 + lane] : 0ull;
            }
            int wreq = i >> 6;
            u64 avail = valw & ~supw;
            bool mybit = (lane == wreq) && ((avail >> (i & 63)) & 1ull);
            if (__ballot(mybit)) supw |= row;
        }
        if (lane < 7) keepm[lane] = valw & ~supw;
    }
    __syncthreads();

    // write per-class candidates (rank tid holds its own data in registers)
    if (tid < WPRE) {
        bool keep = (keepm[tid >> 6] >> (tid & 63)) & 1ull;
        cand_sc[((size_t)(b * NC + c)) * WPRE + tid] = keep ? myval : -1.0f;
        ((float4*)cand_bx)[((size_t)(b * NC + c)) * WPRE + tid] = mybox;
    }
}

// ---------------- Kernel 3: final per-image top-K ----------------
__global__ __launch_bounds__(1024) void topk_kernel(
    const float* __restrict__ cand_sc, const float* __restrict__ cand_bx,
    float* __restrict__ out, int NC, int TOPK, int B)
{
    const int b = blockIdx.x;
    const int tid = threadIdx.x;
    const int T = 1024;
    const int N = NC * WPRE;   // 32000

    __shared__ u32 skey[32000];
    __shared__ u32 hist[256];
    __shared__ u64 cand[256];
    __shared__ u32 sh_prefix;
    __shared__ int sh_r, sh_neq, sh_cnt;

    const float* s = cand_sc + (size_t)b * N;
    int N4 = N >> 2;
    for (int i = tid; i < N4; i += T) {
        float4 f4 = ((const float4*)s)[i];
        skey[i*4+0] = f32_key(f4.x);
        skey[i*4+1] = f32_key(f4.y);
        skey[i*4+2] = f32_key(f4.z);
        skey[i*4+3] = f32_key(f4.w);
    }
    if (tid == 0) sh_cnt = 0;
    __syncthreads();

    u32 pivot; int needed, nge;
    radix_select32([&](int i, u32& k) { k = skey[i]; return true; },
                   N, TOPK, tid, T, hist, &sh_prefix, &sh_r, &sh_neq,
                   pivot, needed, nge);

    if (nge <= 256) {
        for (int i = tid; i < N; i += T) {
            u32 k = skey[i];
            if (k >= pivot) {
                int pos = atomicAdd(&sh_cnt, 1);
                cand[pos] = ((u64)k << 32) | (u64)(~(u32)i);
            }
        }
    } else {
        u32 pivot2; int needed2, nge2;
        radix_select32([&](int i, u32& k) {
                           if (skey[i] != pivot) return false;
                           k = ~(u32)i; return true;
                       },
                       N, needed, tid, T, hist, &sh_prefix, &sh_r, &sh_neq,
                       pivot2, needed2, nge2);
        for (int i = tid; i < N; i += T) {
            u32 k = skey[i];
            if (k > pivot || (k == pivot && (~(u32)i) >= pivot2)) {
                int pos = atomicAdd(&sh_cnt, 1);
                cand[pos] = ((u64)k << 32) | (u64)(~(u32)i);
            }
        }
    }
    __syncthreads();
    int cnt = sh_cnt;
    if (tid < 256 && tid >= cnt) cand[tid] = 0ull;
    __syncthreads();

    // bitonic sort 256 desc (LDS; small cost, 8 blocks only)
    for (int k = 2; k <= 256; k <<= 1) {
        for (int j = k >> 1; j > 0; j >>= 1) {
            if (tid < 256) {
                int ixj = tid ^ j;
                if (ixj > tid) {
                    u64 a = cand[tid], bb = cand[ixj];
                    if (((tid & k) == 0) ? (a < bb) : (a > bb)) {
                        cand[tid] = bb; cand[ixj] = a;
                    }
                }
            }
            __syncthreads();
        }
    }

    if (tid < TOPK) {
        u64 kk = cand[tid];
        float sc = key_f32((u32)(kk >> 32));
        int flat = (int)(~(u32)kk);
        int cls = flat / WPRE;
        float4 bx = ((const float4*)cand_bx)[(size_t)b * N + flat];
        float* ob = out + ((size_t)(b * TOPK + tid)) * 4;
        ob[0] = bx.x; ob[1] = bx.y; ob[2] = bx.z; ob[3] = bx.w;
        out[(size_t)B * TOPK * 4 + (size_t)b * TOPK + tid] = (float)(cls + 1);
        out[(size_t)B * TOPK * 5 + (size_t)b * TOPK + tid] = sc;
    }
}

extern "C" void kernel_launch(void* const* d_in, const int* in_sizes, int n_in,
                              void* d_out, int out_size, void* d_ws, size_t ws_size,
                              hipStream_t stream) {
    const float* locs   = (const float*)d_in[0];
    const float* scores = (const float*)d_in[1];
    const float* priors = (const float*)d_in[2];

    const int P  = in_sizes[2] / 4;          // 8732
    const int B  = in_sizes[0] / (4 * P);    // 8
    const int C  = in_sizes[1] / (B * P);    // 81
    const int NC = C - 1;                    // 80
    const int TOPK = out_size / (B * 6);     // 200

    float* ws      = (float*)d_ws;
    float* dec     = ws;                                    // B*P*4
    float* probs_t = dec + (size_t)B * P * 4;               // B*NC*P
    float* cand_sc = probs_t + (size_t)B * NC * P;          // B*NC*WPRE
    float* cand_bx = cand_sc + (size_t)B * NC * WPRE;       // B*NC*WPRE*4

    dim3 g1((P + 63) / 64, B);
    decode_softmax_kernel<<<g1, 256, 0, stream>>>(locs, scores, priors, dec, probs_t, P, C, NC);

    dim3 g2(NC, B);
    nms_kernel<<<g2, 512, 0, stream>>>(dec, probs_t, cand_sc, cand_bx, P, NC);

    topk_kernel<<<dim3(B), 1024, 0, stream>>>(cand_sc, cand_bx, (float*)d_out, NC, TOPK, B);
}

// Round 4
// 214.041 us; speedup vs baseline: 1.3492x; 1.3492x over previous
//
#include <hip/hip_runtime.h>
#include <cstdint>

typedef unsigned long long u64;
typedef unsigned int u32;

#define WPRE 400
#define MIN_SCORE 0.01f
#define MAX_OVERLAP 0.45f

// Exact predicate: fdiv_rn(inter,uniC) > 0.45f  <=>  (double)inter > MID*(double)uniC
// MID = midpoint(0.45f, nextafterf(0.45f,+inf)) = 0x1.CCCCCDp-2 (exact double).
// 24-bit x 25-bit products are exact in double; real quotient == MID ties to the
// even mantissa 0x3EE66666 == 0.45f -> predicate false -> strict > matches.
#define IOU_MID 0x1.CCCCCDp-2

__device__ __forceinline__ u32 f32_key(float f) {
    u32 u = __float_as_uint(f);
    return (f >= 0.0f) ? (u | 0x80000000u) : ~u;
}
__device__ __forceinline__ float key_f32(u32 k) {
    return __uint_as_float((k & 0x80000000u) ? (k ^ 0x80000000u) : ~k);
}

__device__ __forceinline__ u32 wr_lane(u32 val, int lane, u32 old) {
#if __has_builtin(__builtin_amdgcn_writelane)
    return __builtin_amdgcn_writelane(val, lane, old);
#else
    return ((threadIdx.x & 63) == (u32)lane) ? val : old;
#endif
}

// Exact K-th selection over 32-bit keys (descending), 4 x 8-bit MSD radix.
// Ballot-grouped histogram (skips iterations with zero matches), single-wave
// shfl suffix-scan for the pivot bin -> 3 barriers per pass.
template <typename KF>
__device__ void radix_select32(KF kf, int N, int K, int tid, int T,
                               u32* hist, u32* sh_prefix, int* sh_r, int* sh_neq,
                               u32& pivot, int& needed, int& nge)
{
    const int lane = tid & 63;
    if (tid == 0) { *sh_prefix = 0u; *sh_r = K; *sh_neq = 0; }
    __syncthreads();
    for (int d = 3; d >= 0; --d) {
        u32 pref = *sh_prefix;
        if (tid < 256) hist[tid] = 0u;
        __syncthreads();
        for (int i = tid; i < N; i += T) {
            u32 k = 0u;
            bool ok = kf(i, k);
            bool match = ok && ((d == 3) || (((k ^ pref) >> ((d + 1) * 8)) == 0u));
            u64 m = __ballot(match);
            if (m == 0ull) continue;            // uniform skip (hot in d<3 passes)
            u32 dig = (k >> (d * 8)) & 255u;
            #pragma unroll
            for (int bb = 0; bb < 8; ++bb) {
                u64 bm = __ballot((int)((dig >> bb) & 1u));
                m &= ((dig >> bb) & 1u) ? bm : ~bm;
            }
            if (match) {
                u64 lower = m & ((1ull << lane) - 1ull);
                if (lower == 0ull) atomicAdd(&hist[dig], (u32)__builtin_popcountll(m));
            }
        }
        __syncthreads();
        if (tid < 64) {
            int r = *sh_r;
            u32 h0 = hist[lane*4+0], h1 = hist[lane*4+1];
            u32 h2 = hist[lane*4+2], h3 = hist[lane*4+3];
            u32 s3 = h3, s2 = h2 + s3, s1 = h1 + s2, s0 = h0 + s1;
            u32 t = s0, Tt = s0;
            #pragma unroll
            for (int off = 1; off < 64; off <<= 1) {
                u32 x = __shfl_down(Tt, off, 64);
                Tt += (lane + off < 64) ? x : 0u;
            }
            u32 above = Tt - t;   // sum over lanes > lane
            u32 S0 = s0 + above, S1 = s1 + above, S2 = s2 + above, S3 = s3 + above;
            u32 Sx[5] = { S0, S1, S2, S3, above };
            #pragma unroll
            for (int i2 = 0; i2 < 4; ++i2) {
                if ((int)Sx[i2] >= r && (int)Sx[i2+1] < r) {
                    *sh_prefix = pref | ((u32)(lane * 4 + i2) << (d * 8));
                    *sh_r = r - (int)Sx[i2+1];
                    *sh_neq = (int)(Sx[i2] - Sx[i2+1]);
                }
            }
        }
        __syncthreads();
    }
    pivot = *sh_prefix; needed = *sh_r; nge = (K - needed) + *sh_neq;
    __syncthreads();
}

// ---------------- Kernel 1: decode boxes + softmax (LDS-staged, coalesced) ----------------
__global__ __launch_bounds__(256) void decode_softmax_kernel(
    const float* __restrict__ locs, const float* __restrict__ scores,
    const float* __restrict__ priors, float* __restrict__ dec,
    float* __restrict__ probs_t, int P, int C, int NC)
{
    __shared__ float tile[64 * 81];
    __shared__ float mrow[64], srow[64];
    const int b  = blockIdx.y;
    const int p0 = blockIdx.x * 64;
    const int tid = threadIdx.x;
    const int nrows = min(64, P - p0);
    const int n = nrows * C;

    const float* src = scores + ((size_t)b * P + p0) * C;
    for (int idx = tid; idx < n; idx += 256) tile[idx] = src[idx];

    if (tid < nrows) {
        int p = p0 + tid;
        float4 lc = ((const float4*)locs)[(size_t)b * P + p];
        float4 pr = ((const float4*)priors)[p];
        float cx = lc.x * pr.z / 10.0f + pr.x;
        float cy = lc.y * pr.w / 10.0f + pr.y;
        float w  = expf(lc.z / 5.0f) * pr.z;
        float h  = expf(lc.w / 5.0f) * pr.w;
        ((float4*)dec)[(size_t)b * P + p] =
            make_float4(cx - w * 0.5f, cy - h * 0.5f, cx + w * 0.5f, cy + h * 0.5f);
    }
    __syncthreads();

    if (tid < nrows) {
        const float* row = &tile[tid * C];
        float m = row[0];
        for (int cc = 1; cc < C; ++cc) m = fmaxf(m, row[cc]);
        float ss = 0.f;
        for (int cc = 0; cc < C; ++cc) ss += expf(row[cc] - m);
        mrow[tid] = m; srow[tid] = ss;
    }
    __syncthreads();

    for (int idx = tid; idx < 64 * NC; idx += 256) {
        int r  = idx & 63;
        int cc = idx >> 6;
        if (r < nrows) {
            float v = expf(tile[r * C + cc + 1] - mrow[r]) / srow[r];
            probs_t[((size_t)(b * NC + cc)) * P + p0 + r] = v;
        }
    }
}

// ---------------- Kernel 2: per (class,image) top-400 + NMS ----------------
__global__ __launch_bounds__(512) void nms_kernel(
    const float* __restrict__ dec, const float* __restrict__ probs_t,
    float* __restrict__ cand_sc, float* __restrict__ cand_bx,
    int P, int NC)
{
    const int c = blockIdx.x, b = blockIdx.y;
    const int tid = threadIdx.x;
    const int lane = tid & 63;
    const int wv = tid >> 6;
    const int T = 512;

    // skey (34944 B) is dead after compaction; rowm (400*9*8 = 28800 B) aliases it.
    __shared__ alignas(16) char bufA[8736 * 4];
    u32* skey = (u32*)bufA;
    u64* rowm = (u64*)bufA;
    __shared__ u64 cand[512];
    __shared__ float4 cbox[448];
    __shared__ float ara[448];
    __shared__ u32 hist[256];
    __shared__ u64 validm[7], keepm[7];
    __shared__ u32 sh_prefix;
    __shared__ int sh_r, sh_neq, sh_cnt;

    const float* ps = probs_t + ((size_t)(b * NC + c)) * P;

    // stage masked sortable keys to LDS (vectorized)
    int P4 = P >> 2;
    for (int i = tid; i < P4; i += T) {
        float4 f4 = ((const float4*)ps)[i];
        skey[i*4+0] = f32_key(f4.x > MIN_SCORE ? f4.x : -1.0f);
        skey[i*4+1] = f32_key(f4.y > MIN_SCORE ? f4.y : -1.0f);
        skey[i*4+2] = f32_key(f4.z > MIN_SCORE ? f4.z : -1.0f);
        skey[i*4+3] = f32_key(f4.w > MIN_SCORE ? f4.w : -1.0f);
    }
    for (int i = (P4 << 2) + tid; i < P; i += T) {
        float f = ps[i];
        skey[i] = f32_key(f > MIN_SCORE ? f : -1.0f);
    }
    if (tid == 0) sh_cnt = 0;
    __syncthreads();

    u32 pivot; int needed, nge;
    radix_select32([&](int i, u32& k) { k = skey[i]; return true; },
                   P, WPRE, tid, T, hist, &sh_prefix, &sh_r, &sh_neq,
                   pivot, needed, nge);

    if (nge <= 512) {
        for (int i = tid; i < P; i += T) {
            u32 k = skey[i];
            if (k >= pivot) {
                int pos = atomicAdd(&sh_cnt, 1);
                cand[pos] = ((u64)k << 32) | (u64)(~(u32)i);
            }
        }
    } else {
        // tie flood at pivot: exact secondary select on index key among equals
        u32 pivot2; int needed2, nge2;
        radix_select32([&](int i, u32& k) {
                           if (skey[i] != pivot) return false;
                           k = ~(u32)i; return true;
                       },
                       P, needed, tid, T, hist, &sh_prefix, &sh_r, &sh_neq,
                       pivot2, needed2, nge2);
        for (int i = tid; i < P; i += T) {
            u32 k = skey[i];
            if (k > pivot || (k == pivot && (~(u32)i) >= pivot2)) {
                int pos = atomicAdd(&sh_cnt, 1);
                cand[pos] = ((u64)k << 32) | (u64)(~(u32)i);
            }
        }
    }
    __syncthreads();
    const int cnt = sh_cnt;            // in [400, 512]
    u64 v = (tid < cnt) ? cand[tid] : 0ull;

    // register bitonic sort 512 desc: shfl within wave, LDS only for j>=64
    for (int k = 2; k <= 512; k <<= 1) {
        for (int j = k >> 1; j > 0; j >>= 1) {
            u64 p;
            if (j < 64) {
                p = __shfl_xor(v, j, 64);
            } else {
                __syncthreads();
                cand[tid] = v;
                __syncthreads();
                p = cand[tid ^ j];
            }
            bool takeMax = (((tid & k) == 0) == ((tid & j) == 0));
            v = takeMax ? (v > p ? v : p) : (v > p ? p : v);
        }
    }
    __syncthreads();   // all reads of cand done; skey/rowm region free after this

    // unpack rank-tid candidate (in register) into SoA; slots 400..447 zero-pad
    float4 mybox = make_float4(0.f, 0.f, 0.f, 0.f);
    float myval = -1.0f;
    if (tid < 448) {
        if (tid < WPRE) {
            myval = key_f32((u32)(v >> 32));
            int p = (int)(~(u32)v);
            mybox = ((const float4*)dec)[(size_t)b * P + p];
        }
        cbox[tid] = mybox;
        ara[tid] = (mybox.z - mybox.x) * (mybox.w - mybox.y);
        u64 mk = __ballot(myval > MIN_SCORE);
        if (lane == 0) validm[tid >> 6] = mk;
    }
    __syncthreads();

    // upper-triangle suppression bit-matrix, 64x64 register tiles.
    // lane holds box_j (j = 64w+lane); per row i: broadcast LDS reads, exact
    // double-compare predicate, v_writelane row capture.
    for (int t = wv; t < 28; t += 8) {
        int r = 0, base = 0;
        while (t - base >= 7 - r) { base += 7 - r; ++r; }
        int w = r + (t - base);
        int nrows = (r == 6) ? (WPRE - 384) : 64;
        int j = (w << 6) + lane;
        float4 bj = cbox[j];
        float aj = ara[j];
        u32 rlo = 0u, rhi = 0u;
        #pragma unroll 8
        for (int k2 = 0; k2 < nrows; ++k2) {
            int i = (r << 6) + k2;
            float4 bi = cbox[i];
            float ai = ara[i];
            float lx = fmaxf(bi.x, bj.x);
            float ly = fmaxf(bi.y, bj.y);
            float rx = fminf(bi.z, bj.z);
            float ry = fminf(bi.w, bj.w);
            float ww = fmaxf(rx - lx, 0.f);
            float hh = fmaxf(ry - ly, 0.f);
            float inter = ww * hh;
            float uniC = fmaxf((ai + aj) - inter, 1e-10f);
            bool pred = (double)inter > IOU_MID * (double)uniC;
            u64 vote = __ballot(pred);
            rlo = wr_lane((u32)vote, k2, rlo);
            rhi = wr_lane((u32)(vote >> 32), k2, rhi);
        }
        u64 myrow = ((u64)rhi << 32) | rlo;
        if (r == w) myrow &= ~(1ull << lane);      // diagonal
        if (lane < nrows) rowm[(size_t)((r << 6) + lane) * 9 + w] = myrow;
    }
    __syncthreads();

    // serial scan in ONE wave, zero barriers; lower-tri words substituted 0
    if (tid < 64) {
        u64 supw = 0ull;
        u64 valw = (lane < 7) ? validm[lane] : 0ull;
        u64 row_next = (lane < 7) ? rowm[lane] : 0ull;    // i=0
        for (int i = 0; i < WPRE; ++i) {
            u64 row = row_next;
            int inext = i + 1;
            if (inext < WPRE) {
                int wq = inext >> 6;
                row_next = (lane < 7 && lane >= wq) ? rowm[(size_t)inext * 9 + lane] : 0ull;
            }
            int wreq = i >> 6;
            u64 avail = valw & ~supw;
            bool mybit = (lane == wreq) && ((avail >> (i & 63)) & 1ull);
            if (__ballot(mybit)) supw |= row;
        }
        if (lane < 7) keepm[lane] = valw & ~supw;
    }
    __syncthreads();

    // write per-class candidates (rank tid holds its own data in registers)
    if (tid < WPRE) {
        bool keep = (keepm[tid >> 6] >> (tid & 63)) & 1ull;
        cand_sc[((size_t)(b * NC + c)) * WPRE + tid] = keep ? myval : -1.0f;
        ((float4*)cand_bx)[((size_t)(b * NC + c)) * WPRE + tid] = mybox;
    }
}

// ---------------- Kernel 3: final per-image top-K ----------------
__global__ __launch_bounds__(1024) void topk_kernel(
    const float* __restrict__ cand_sc, const float* __restrict__ cand_bx,
    float* __restrict__ out, int NC, int TOPK, int B)
{
    const int b = blockIdx.x;
    const int tid = threadIdx.x;
    const int T = 1024;
    const int N = NC * WPRE;   // 32000

    __shared__ u32 skey[32000];
    __shared__ u32 hist[256];
    __shared__ u64 cand[256];
    __shared__ u32 sh_prefix;
    __shared__ int sh_r, sh_neq, sh_cnt;

    const float* s = cand_sc + (size_t)b * N;
    int N4 = N >> 2;
    for (int i = tid; i < N4; i += T) {
        float4 f4 = ((const float4*)s)[i];
        skey[i*4+0] = f32_key(f4.x);
        skey[i*4+1] = f32_key(f4.y);
        skey[i*4+2] = f32_key(f4.z);
        skey[i*4+3] = f32_key(f4.w);
    }
    if (tid == 0) sh_cnt = 0;
    __syncthreads();

    u32 pivot; int needed, nge;
    radix_select32([&](int i, u32& k) { k = skey[i]; return true; },
                   N, TOPK, tid, T, hist, &sh_prefix, &sh_r, &sh_neq,
                   pivot, needed, nge);

    if (nge <= 256) {
        for (int i = tid; i < N; i += T) {
            u32 k = skey[i];
            if (k >= pivot) {
                int pos = atomicAdd(&sh_cnt, 1);
                cand[pos] = ((u64)k << 32) | (u64)(~(u32)i);
            }
        }
    } else {
        u32 pivot2; int needed2, nge2;
        radix_select32([&](int i, u32& k) {
                           if (skey[i] != pivot) return false;
                           k = ~(u32)i; return true;
                       },
                       N, needed, tid, T, hist, &sh_prefix, &sh_r, &sh_neq,
                       pivot2, needed2, nge2);
        for (int i = tid; i < N; i += T) {
            u32 k = skey[i];
            if (k > pivot || (k == pivot && (~(u32)i) >= pivot2)) {
                int pos = atomicAdd(&sh_cnt, 1);
                cand[pos] = ((u64)k << 32) | (u64)(~(u32)i);
            }
        }
    }
    __syncthreads();
    int cnt = sh_cnt;
    u64 v = (tid < 256 && tid < cnt) ? cand[tid] : 0ull;

    // register bitonic sort 256 desc in 4 waves (others just hit the barriers)
    for (int k = 2; k <= 256; k <<= 1) {
        for (int j = k >> 1; j > 0; j >>= 1) {
            u64 p;
            if (j < 64) {
                p = __shfl_xor(v, j, 64);
            } else {
                __syncthreads();
                if (tid < 256) cand[tid] = v;
                __syncthreads();
                p = (tid < 256) ? cand[tid ^ j] : 0ull;
            }
            bool takeMax = (((tid & k) == 0) == ((tid & j) == 0));
            v = takeMax ? (v > p ? v : p) : (v > p ? p : v);
        }
    }

    if (tid < TOPK) {
        float sc = key_f32((u32)(v >> 32));
        int flat = (int)(~(u32)v);
        int cls = flat / WPRE;
        float4 bx = ((const float4*)cand_bx)[(size_t)b * N + flat];
        float* ob = out + ((size_t)(b * TOPK + tid)) * 4;
        ob[0] = bx.x; ob[1] = bx.y; ob[2] = bx.z; ob[3] = bx.w;
        out[(size_t)B * TOPK * 4 + (size_t)b * TOPK + tid] = (float)(cls + 1);
        out[(size_t)B * TOPK * 5 + (size_t)b * TOPK + tid] = sc;
    }
}

extern "C" void kernel_launch(void* const* d_in, const int* in_sizes, int n_in,
                              void* d_out, int out_size, void* d_ws, size_t ws_size,
                              hipStream_t stream) {
    const float* locs   = (const float*)d_in[0];
    const float* scores = (const float*)d_in[1];
    const float* priors = (const float*)d_in[2];

    const int P  = in_sizes[2] / 4;          // 8732
    const int B  = in_sizes[0] / (4 * P);    // 8
    const int C  = in_sizes[1] / (B * P);    // 81
    const int NC = C - 1;                    // 80
    const int TOPK = out_size / (B * 6);     // 200

    float* ws      = (float*)d_ws;
    float* dec     = ws;                                    // B*P*4
    float* probs_t = dec + (size_t)B * P * 4;               // B*NC*P
    float* cand_sc = probs_t + (size_t)B * NC * P;          // B*NC*WPRE
    float* cand_bx = cand_sc + (size_t)B * NC * WPRE;       // B*NC*WPRE*4

    dim3 g1((P + 63) / 64, B);
    decode_softmax_kernel<<<g1, 256, 0, stream>>>(locs, scores, priors, dec, probs_t, P, C, NC);

    dim3 g2(NC, B);
    nms_kernel<<<g2, 512, 0, stream>>>(dec, probs_t, cand_sc, cand_bx, P, NC);

    topk_kernel<<<dim3(B), 1024, 0, stream>>>(cand_sc, cand_bx, (float*)d_out, NC, TOPK, B);
}

// Round 5
// 201.560 us; speedup vs baseline: 1.4328x; 1.0619x over previous
//
#include <hip/hip_runtime.h>
#include <cstdint>

typedef unsigned long long u64;
typedef unsigned int u32;

#define WPRE 400
#define MIN_SCORE 0.01f
#define MAX_OVERLAP 0.45f

// Exact predicate: fdiv_rn(inter,uniC) > 0.45f  <=>  (double)inter > MID*(double)uniC
// MID = midpoint(0.45f, nextafterf(0.45f,+inf)) = 0x1.CCCCCDp-2 (exact double).
#define IOU_MID 0x1.CCCCCDp-2

__device__ __forceinline__ u32 f32_key(float f) {
    u32 u = __float_as_uint(f);
    return (f >= 0.0f) ? (u | 0x80000000u) : ~u;
}
__device__ __forceinline__ float key_f32(u32 k) {
    return __uint_as_float((k & 0x80000000u) ? (k ^ 0x80000000u) : ~k);
}

__device__ __forceinline__ u32 wr_lane(u32 val, int lane, u32 old) {
#if __has_builtin(__builtin_amdgcn_writelane)
    return __builtin_amdgcn_writelane(val, lane, old);
#else
    return ((threadIdx.x & 63) == (u32)lane) ? val : old;
#endif
}

// Exact K-th selection over 32-bit keys (descending), 4 x 8-bit MSD radix.
// Ballot-grouped histogram; single-wave shfl suffix-scan for pivot bin.
template <typename KF>
__device__ void radix_select32(KF kf, int N, int K, int tid, int T,
                               u32* hist, u32* sh_prefix, int* sh_r, int* sh_neq,
                               u32& pivot, int& needed, int& nge)
{
    const int lane = tid & 63;
    if (tid == 0) { *sh_prefix = 0u; *sh_r = K; *sh_neq = 0; }
    __syncthreads();
    for (int d = 3; d >= 0; --d) {
        u32 pref = *sh_prefix;
        if (tid < 256) hist[tid] = 0u;
        __syncthreads();
        for (int i = tid; i < N; i += T) {
            u32 k = 0u;
            bool ok = kf(i, k);
            bool match = ok && ((d == 3) || (((k ^ pref) >> ((d + 1) * 8)) == 0u));
            u64 m = __ballot(match);
            if (m == 0ull) continue;            // uniform skip
            u32 dig = (k >> (d * 8)) & 255u;
            #pragma unroll
            for (int bb = 0; bb < 8; ++bb) {
                u64 bm = __ballot((int)((dig >> bb) & 1u));
                m &= ((dig >> bb) & 1u) ? bm : ~bm;
            }
            if (match) {
                u64 lower = m & ((1ull << lane) - 1ull);
                if (lower == 0ull) atomicAdd(&hist[dig], (u32)__builtin_popcountll(m));
            }
        }
        __syncthreads();
        if (tid < 64) {
            int r = *sh_r;
            u32 h0 = hist[lane*4+0], h1 = hist[lane*4+1];
            u32 h2 = hist[lane*4+2], h3 = hist[lane*4+3];
            u32 s3 = h3, s2 = h2 + s3, s1 = h1 + s2, s0 = h0 + s1;
            u32 t = s0, Tt = s0;
            #pragma unroll
            for (int off = 1; off < 64; off <<= 1) {
                u32 x = __shfl_down(Tt, off, 64);
                Tt += (lane + off < 64) ? x : 0u;
            }
            u32 above = Tt - t;
            u32 S0 = s0 + above, S1 = s1 + above, S2 = s2 + above, S3 = s3 + above;
            u32 Sx[5] = { S0, S1, S2, S3, above };
            #pragma unroll
            for (int i2 = 0; i2 < 4; ++i2) {
                if ((int)Sx[i2] >= r && (int)Sx[i2+1] < r) {
                    *sh_prefix = pref | ((u32)(lane * 4 + i2) << (d * 8));
                    *sh_r = r - (int)Sx[i2+1];
                    *sh_neq = (int)(Sx[i2] - Sx[i2+1]);
                }
            }
        }
        __syncthreads();
    }
    pivot = *sh_prefix; needed = *sh_r; nge = (K - needed) + *sh_neq;
    __syncthreads();
}

// ---------------- Kernel 1: decode boxes + softmax ----------------
__global__ __launch_bounds__(256) void decode_softmax_kernel(
    const float* __restrict__ locs, const float* __restrict__ scores,
    const float* __restrict__ priors, float* __restrict__ dec,
    float* __restrict__ probs_t, int P, int C, int NC)
{
    __shared__ float tile[64 * 81];
    __shared__ float mrow[64], srow[64];
    const int b  = blockIdx.y;
    const int p0 = blockIdx.x * 64;
    const int tid = threadIdx.x;
    const int nrows = min(64, P - p0);
    const int n = nrows * C;

    const float* src = scores + ((size_t)b * P + p0) * C;
    for (int idx = tid; idx < n; idx += 256) tile[idx] = src[idx];

    if (tid < nrows) {
        int p = p0 + tid;
        float4 lc = ((const float4*)locs)[(size_t)b * P + p];
        float4 pr = ((const float4*)priors)[p];
        float cx = lc.x * pr.z / 10.0f + pr.x;
        float cy = lc.y * pr.w / 10.0f + pr.y;
        float w  = expf(lc.z / 5.0f) * pr.z;
        float h  = expf(lc.w / 5.0f) * pr.w;
        ((float4*)dec)[(size_t)b * P + p] =
            make_float4(cx - w * 0.5f, cy - h * 0.5f, cx + w * 0.5f, cy + h * 0.5f);
    }
    __syncthreads();

    if (tid < nrows) {
        const float* row = &tile[tid * C];
        float m = row[0];
        for (int cc = 1; cc < C; ++cc) m = fmaxf(m, row[cc]);
        float ss = 0.f;
        for (int cc = 0; cc < C; ++cc) ss += expf(row[cc] - m);
        mrow[tid] = m; srow[tid] = ss;
    }
    __syncthreads();

    for (int idx = tid; idx < 64 * NC; idx += 256) {
        int r  = idx & 63;
        int cc = idx >> 6;
        if (r < nrows) {
            float v = expf(tile[r * C + cc + 1] - mrow[r]) / srow[r];
            probs_t[((size_t)(b * NC + cc)) * P + p0 + r] = v;
        }
    }
}

// ---------------- Kernel 2a: per (class,image) exact top-400 selection ----------------
__global__ __launch_bounds__(512) void select_kernel(
    const float* __restrict__ probs_t, u64* __restrict__ cand512,
    int* __restrict__ cnt512, int P, int NC)
{
    const int c = blockIdx.x, b = blockIdx.y;
    const int tid = threadIdx.x;
    const int T = 512;

    __shared__ u32 skey[8736];
    __shared__ u32 hist[256];
    __shared__ u32 sh_prefix;
    __shared__ int sh_r, sh_neq, sh_cnt;

    const float* ps = probs_t + ((size_t)(b * NC + c)) * P;
    u64* outk = cand512 + (size_t)(b * NC + c) * 512;

    int P4 = P >> 2;
    for (int i = tid; i < P4; i += T) {
        float4 f4 = ((const float4*)ps)[i];
        skey[i*4+0] = f32_key(f4.x > MIN_SCORE ? f4.x : -1.0f);
        skey[i*4+1] = f32_key(f4.y > MIN_SCORE ? f4.y : -1.0f);
        skey[i*4+2] = f32_key(f4.z > MIN_SCORE ? f4.z : -1.0f);
        skey[i*4+3] = f32_key(f4.w > MIN_SCORE ? f4.w : -1.0f);
    }
    for (int i = (P4 << 2) + tid; i < P; i += T) {
        float f = ps[i];
        skey[i] = f32_key(f > MIN_SCORE ? f : -1.0f);
    }
    if (tid == 0) sh_cnt = 0;
    __syncthreads();

    u32 pivot; int needed, nge;
    radix_select32([&](int i, u32& k) { k = skey[i]; return true; },
                   P, WPRE, tid, T, hist, &sh_prefix, &sh_r, &sh_neq,
                   pivot, needed, nge);

    if (nge <= 512) {
        for (int i = tid; i < P; i += T) {
            u32 k = skey[i];
            if (k >= pivot) {
                int pos = atomicAdd(&sh_cnt, 1);
                outk[pos] = ((u64)k << 32) | (u64)(~(u32)i);
            }
        }
    } else {
        u32 pivot2; int needed2, nge2;
        radix_select32([&](int i, u32& k) {
                           if (skey[i] != pivot) return false;
                           k = ~(u32)i; return true;
                       },
                       P, needed, tid, T, hist, &sh_prefix, &sh_r, &sh_neq,
                       pivot2, needed2, nge2);
        for (int i = tid; i < P; i += T) {
            u32 k = skey[i];
            if (k > pivot || (k == pivot && (~(u32)i) >= pivot2)) {
                int pos = atomicAdd(&sh_cnt, 1);
                outk[pos] = ((u64)k << 32) | (u64)(~(u32)i);
            }
        }
    }
    __syncthreads();
    int cnt = sh_cnt;              // in [400, 512]
    if (tid >= cnt) outk[tid] = 0ull;
    if (tid == 0) cnt512[b * NC + c] = cnt;
}

// ---------------- Kernel 2b: sort + IoU matrix + serial NMS scan ----------------
__global__ __launch_bounds__(512) void nms_kernel(
    const float* __restrict__ dec, const u64* __restrict__ cand512,
    const int* __restrict__ cnt512,
    float* __restrict__ cand_sc, float* __restrict__ cand_bx,
    int P, int NC)
{
    const int c = blockIdx.x, b = blockIdx.y;
    const int tid = threadIdx.x;
    const int lane = tid & 63;
    const int wv = tid >> 6;
    const int T = 512;

    __shared__ u64 cand[512];
    __shared__ float4 cbox[448];
    __shared__ float ara[448];
    __shared__ u64 rowm[WPRE * 7];      // stride 7: words w in [0,7)
    __shared__ u64 validm[7], keepm[7];

    const int cnt = cnt512[b * NC + c];
    u64 v = (tid < cnt) ? cand512[(size_t)(b * NC + c) * 512 + tid] : 0ull;

    // register bitonic sort 512 desc: shfl within wave, LDS for j>=64
    for (int k = 2; k <= 512; k <<= 1) {
        for (int j = k >> 1; j > 0; j >>= 1) {
            u64 p;
            if (j < 64) {
                p = __shfl_xor(v, j, 64);
            } else {
                __syncthreads();
                cand[tid] = v;
                __syncthreads();
                p = cand[tid ^ j];
            }
            bool takeMax = (((tid & k) == 0) == ((tid & j) == 0));
            v = takeMax ? (v > p ? v : p) : (v > p ? p : v);
        }
    }
    __syncthreads();

    // unpack rank-tid candidate into SoA; slots 400..447 zero-pad
    float4 mybox = make_float4(0.f, 0.f, 0.f, 0.f);
    float myval = -1.0f;
    if (tid < 448) {
        if (tid < WPRE) {
            myval = key_f32((u32)(v >> 32));
            int p = (int)(~(u32)v);
            mybox = ((const float4*)dec)[(size_t)b * P + p];
        }
        cbox[tid] = mybox;
        ara[tid] = (mybox.z - mybox.x) * (mybox.w - mybox.y);
        u64 mk = __ballot(myval > MIN_SCORE);
        if (lane == 0) validm[tid >> 6] = mk;
    }
    __syncthreads();

    // upper-triangle suppression bit-matrix, 64x64 register tiles
    for (int t = wv; t < 28; t += 8) {
        int r = 0, base = 0;
        while (t - base >= 7 - r) { base += 7 - r; ++r; }
        int w = r + (t - base);
        int nrows = (r == 6) ? (WPRE - 384) : 64;
        int j = (w << 6) + lane;
        float4 bj = cbox[j];
        float aj = ara[j];
        u32 rlo = 0u, rhi = 0u;
        #pragma unroll 8
        for (int k2 = 0; k2 < nrows; ++k2) {
            int i = (r << 6) + k2;
            float4 bi = cbox[i];
            float ai = ara[i];
            float lx = fmaxf(bi.x, bj.x);
            float ly = fmaxf(bi.y, bj.y);
            float rx = fminf(bi.z, bj.z);
            float ry = fminf(bi.w, bj.w);
            float ww = fmaxf(rx - lx, 0.f);
            float hh = fmaxf(ry - ly, 0.f);
            float inter = ww * hh;
            float uniC = fmaxf((ai + aj) - inter, 1e-10f);
            bool pred = (double)inter > IOU_MID * (double)uniC;
            u64 vote = __ballot(pred);
            rlo = wr_lane((u32)vote, k2, rlo);
            rhi = wr_lane((u32)(vote >> 32), k2, rhi);
        }
        u64 myrow = ((u64)rhi << 32) | rlo;
        if (r == w) myrow &= ~(1ull << lane);      // diagonal
        if (lane < nrows) rowm[(size_t)((r << 6) + lane) * 7 + w] = myrow;
    }
    __syncthreads();

    // serial scan in ONE wave, zero barriers; lower-tri words substituted 0
    if (tid < 64) {
        u64 supw = 0ull;
        u64 valw = (lane < 7) ? validm[lane] : 0ull;
        u64 row_next = (lane < 7) ? rowm[lane] : 0ull;    // i=0
        for (int i = 0; i < WPRE; ++i) {
            u64 row = row_next;
            int inext = i + 1;
            if (inext < WPRE) {
                int wq = inext >> 6;
                row_next = (lane < 7 && lane >= wq) ? rowm[(size_t)inext * 7 + lane] : 0ull;
            }
            int wreq = i >> 6;
            u64 avail = valw & ~supw;
            bool mybit = (lane == wreq) && ((avail >> (i & 63)) & 1ull);
            if (__ballot(mybit)) supw |= row;
        }
        if (lane < 7) keepm[lane] = valw & ~supw;
    }
    __syncthreads();

    if (tid < WPRE) {
        bool keep = (keepm[tid >> 6] >> (tid & 63)) & 1ull;
        cand_sc[((size_t)(b * NC + c)) * WPRE + tid] = keep ? myval : -1.0f;
        ((float4*)cand_bx)[((size_t)(b * NC + c)) * WPRE + tid] = mybox;
    }
}

// ---------------- Kernel 3a: per (image, 8-class group) exact top-200 ----------------
__global__ __launch_bounds__(512) void topkA_kernel(
    const float* __restrict__ cand_sc, u64* __restrict__ wsA,
    int NC, int TOPK, int GS, int NG)
{
    const int g = blockIdx.x, b = blockIdx.y;
    const int tid = threadIdx.x;
    const int T = 512;
    const int N = GS;                 // 3200
    const u32 fbase = (u32)(g * GS);  // global flat offset within image

    __shared__ u32 hist[256];
    __shared__ u32 sh_prefix;
    __shared__ int sh_r, sh_neq, sh_cnt;

    const float* s = cand_sc + (size_t)b * NC * WPRE + (size_t)g * GS;
    u64* outg = wsA + (size_t)(b * NG + g) * 256;

    if (tid == 0) sh_cnt = 0;
    __syncthreads();

    u32 pivot; int needed, nge;
    radix_select32([&](int i, u32& k) { k = f32_key(s[i]); return true; },
                   N, TOPK, tid, T, hist, &sh_prefix, &sh_r, &sh_neq,
                   pivot, needed, nge);

    if (nge <= 256) {
        for (int i = tid; i < N; i += T) {
            u32 k = f32_key(s[i]);
            if (k >= pivot) {
                int pos = atomicAdd(&sh_cnt, 1);
                outg[pos] = ((u64)k << 32) | (u64)(~(fbase + (u32)i));
            }
        }
    } else {
        u32 pivot2; int needed2, nge2;
        radix_select32([&](int i, u32& k) {
                           if (f32_key(s[i]) != pivot) return false;
                           k = ~(u32)i; return true;
                       },
                       N, needed, tid, T, hist, &sh_prefix, &sh_r, &sh_neq,
                       pivot2, needed2, nge2);
        for (int i = tid; i < N; i += T) {
            u32 k = f32_key(s[i]);
            if (k > pivot || (k == pivot && (~(u32)i) >= pivot2)) {
                int pos = atomicAdd(&sh_cnt, 1);
                outg[pos] = ((u64)k << 32) | (u64)(~(fbase + (u32)i));
            }
        }
    }
    __syncthreads();
    int cnt = sh_cnt;   // in [TOPK, 256]
    if (tid < 256 && tid >= cnt) outg[tid] = 0ull;
}

// ---------------- Kernel 3b: merge groups, exact top-200, emit ----------------
__global__ __launch_bounds__(256) void topkB_kernel(
    const u64* __restrict__ wsA, const float* __restrict__ cand_bx,
    float* __restrict__ out, int NC, int TOPK, int B, int NG)
{
    const int b = blockIdx.x;
    const int tid = threadIdx.x;
    const int T = 256;
    const int N = NG * 256;           // 2560

    __shared__ u64 keys[2560];
    __shared__ u32 hist[256];
    __shared__ u64 cand[256];
    __shared__ u32 sh_prefix;
    __shared__ int sh_r, sh_neq, sh_cnt;

    const u64* src = wsA + (size_t)b * N;
    for (int i = tid; i < N; i += T) keys[i] = src[i];
    if (tid == 0) sh_cnt = 0;
    __syncthreads();

    u32 pivot; int needed, nge;
    radix_select32([&](int i, u32& k) { k = (u32)(keys[i] >> 32); return true; },
                   N, TOPK, tid, T, hist, &sh_prefix, &sh_r, &sh_neq,
                   pivot, needed, nge);

    if (nge <= 256) {
        for (int i = tid; i < N; i += T) {
            u64 kk = keys[i];
            if ((u32)(kk >> 32) >= pivot) {
                int pos = atomicAdd(&sh_cnt, 1);
                cand[pos] = kk;
            }
        }
    } else {
        // hi-word tie flood: secondary select on low word (~flat) among equals
        u32 pivot2; int needed2, nge2;
        radix_select32([&](int i, u32& k) {
                           u64 kk = keys[i];
                           if ((u32)(kk >> 32) != pivot) return false;
                           k = (u32)kk; return true;
                       },
                       N, needed, tid, T, hist, &sh_prefix, &sh_r, &sh_neq,
                       pivot2, needed2, nge2);
        for (int i = tid; i < N; i += T) {
            u64 kk = keys[i];
            u32 hi = (u32)(kk >> 32);
            if (hi > pivot || (hi == pivot && ((u32)kk) >= pivot2)) {
                int pos = atomicAdd(&sh_cnt, 1);
                cand[pos] = kk;
            }
        }
    }
    __syncthreads();
    int cnt = sh_cnt;
    u64 v = (tid < cnt) ? cand[tid] : 0ull;

    // register bitonic sort 256 desc (full u64 -> exact (score, flat) order)
    for (int k = 2; k <= 256; k <<= 1) {
        for (int j = k >> 1; j > 0; j >>= 1) {
            u64 p;
            if (j < 64) {
                p = __shfl_xor(v, j, 64);
            } else {
                __syncthreads();
                cand[tid] = v;
                __syncthreads();
                p = cand[tid ^ j];
            }
            bool takeMax = (((tid & k) == 0) == ((tid & j) == 0));
            v = takeMax ? (v > p ? v : p) : (v > p ? p : v);
        }
    }

    if (tid < TOPK) {
        float sc = key_f32((u32)(v >> 32));
        int flat = (int)(~(u32)v);
        int cls = flat / WPRE;
        float4 bx = ((const float4*)cand_bx)[(size_t)b * NC * WPRE + flat];
        float* ob = out + ((size_t)(b * TOPK + tid)) * 4;
        ob[0] = bx.x; ob[1] = bx.y; ob[2] = bx.z; ob[3] = bx.w;
        out[(size_t)B * TOPK * 4 + (size_t)b * TOPK + tid] = (float)(cls + 1);
        out[(size_t)B * TOPK * 5 + (size_t)b * TOPK + tid] = sc;
    }
}

extern "C" void kernel_launch(void* const* d_in, const int* in_sizes, int n_in,
                              void* d_out, int out_size, void* d_ws, size_t ws_size,
                              hipStream_t stream) {
    const float* locs   = (const float*)d_in[0];
    const float* scores = (const float*)d_in[1];
    const float* priors = (const float*)d_in[2];

    const int P  = in_sizes[2] / 4;          // 8732
    const int B  = in_sizes[0] / (4 * P);    // 8
    const int C  = in_sizes[1] / (B * P);    // 81
    const int NC = C - 1;                    // 80
    const int TOPK = out_size / (B * 6);     // 200
    const int NG = 10;                       // class groups per image
    const int GS = (NC * WPRE) / NG;         // 3200 entries per group

    float* ws      = (float*)d_ws;
    float* dec     = ws;                                    // B*P*4
    float* probs_t = dec + (size_t)B * P * 4;               // B*NC*P
    float* cand_sc = probs_t + (size_t)B * NC * P;          // B*NC*WPRE
    float* cand_bx = cand_sc + (size_t)B * NC * WPRE;       // B*NC*WPRE*4
    u64*   cand512 = (u64*)(cand_bx + (size_t)B * NC * WPRE * 4);  // B*NC*512 u64
    int*   cnt512  = (int*)(cand512 + (size_t)B * NC * 512);       // B*NC
    u64*   wsA     = cand512;   // stage-A keys reuse cand512 region (stream-ordered dead)

    dim3 g1((P + 63) / 64, B);
    decode_softmax_kernel<<<g1, 256, 0, stream>>>(locs, scores, priors, dec, probs_t, P, C, NC);

    dim3 g2(NC, B);
    select_kernel<<<g2, 512, 0, stream>>>(probs_t, cand512, cnt512, P, NC);
    nms_kernel<<<g2, 512, 0, stream>>>(dec, cand512, cnt512, cand_sc, cand_bx, P, NC);

    dim3 g3(NG, B);
    topkA_kernel<<<g3, 512, 0, stream>>>(cand_sc, wsA, NC, TOPK, GS, NG);
    topkB_kernel<<<dim3(B), 256, 0, stream>>>(wsA, cand_bx, (float*)d_out, NC, TOPK, B, NG);
}

// Round 6
// 180.962 us; speedup vs baseline: 1.5959x; 1.1138x over previous
//
#include <hip/hip_runtime.h>
#include <cstdint>

typedef unsigned long long u64;
typedef unsigned int u32;

#define WPRE 400
#define MIN_SCORE 0.01f
#define MAX_OVERLAP 0.45f

// Exact predicate: fdiv_rn(inter,uniC) > 0.45f  <=>  (double)inter > MID*(double)uniC
// MID = midpoint(0.45f, nextafterf(0.45f,+inf)) = 0x1.CCCCCDp-2 (exact double).
#define IOU_MID 0x1.CCCCCDp-2

__device__ __forceinline__ u32 f32_key(float f) {
    u32 u = __float_as_uint(f);
    return (f >= 0.0f) ? (u | 0x80000000u) : ~u;
}
__device__ __forceinline__ float key_f32(u32 k) {
    return __uint_as_float((k & 0x80000000u) ? (k ^ 0x80000000u) : ~k);
}

__device__ __forceinline__ u32 wr_lane(u32 val, int lane, u32 old) {
#if __has_builtin(__builtin_amdgcn_writelane)
    return __builtin_amdgcn_writelane(val, lane, old);
#else
    return ((threadIdx.x & 63) == (u32)lane) ? val : old;
#endif
}
__device__ __forceinline__ u64 rd_lane64(u64 v, int lane) {
#if __has_builtin(__builtin_amdgcn_readlane)
    u32 lo = __builtin_amdgcn_readlane((u32)v, lane);
    u32 hi = __builtin_amdgcn_readlane((u32)(v >> 32), lane);
    return ((u64)hi << 32) | lo;
#else
    return __shfl(v, lane, 64);
#endif
}
__device__ __forceinline__ u64 rfl64(u64 v) {
#if __has_builtin(__builtin_amdgcn_readfirstlane)
    u32 lo = __builtin_amdgcn_readfirstlane((u32)v);
    u32 hi = __builtin_amdgcn_readfirstlane((u32)(v >> 32));
    return ((u64)hi << 32) | lo;
#else
    return v;
#endif
}

// Exact K-th selection over 32-bit keys (descending), 4 x 8-bit MSD radix.
// Ballot-grouped histogram; single-wave shfl suffix-scan for pivot bin.
template <typename KF>
__device__ void radix_select32(KF kf, int N, int K, int tid, int T,
                               u32* hist, u32* sh_prefix, int* sh_r, int* sh_neq,
                               u32& pivot, int& needed, int& nge)
{
    const int lane = tid & 63;
    if (tid == 0) { *sh_prefix = 0u; *sh_r = K; *sh_neq = 0; }
    __syncthreads();
    for (int d = 3; d >= 0; --d) {
        u32 pref = *sh_prefix;
        if (tid < 256) hist[tid] = 0u;
        __syncthreads();
        for (int i = tid; i < N; i += T) {
            u32 k = 0u;
            bool ok = kf(i, k);
            bool match = ok && ((d == 3) || (((k ^ pref) >> ((d + 1) * 8)) == 0u));
            u64 m = __ballot(match);
            if (m == 0ull) continue;            // uniform skip
            u32 dig = (k >> (d * 8)) & 255u;
            #pragma unroll
            for (int bb = 0; bb < 8; ++bb) {
                u64 bm = __ballot((int)((dig >> bb) & 1u));
                m &= ((dig >> bb) & 1u) ? bm : ~bm;
            }
            if (match) {
                u64 lower = m & ((1ull << lane) - 1ull);
                if (lower == 0ull) atomicAdd(&hist[dig], (u32)__builtin_popcountll(m));
            }
        }
        __syncthreads();
        if (tid < 64) {
            int r = *sh_r;
            u32 h0 = hist[lane*4+0], h1 = hist[lane*4+1];
            u32 h2 = hist[lane*4+2], h3 = hist[lane*4+3];
            u32 s3 = h3, s2 = h2 + s3, s1 = h1 + s2, s0 = h0 + s1;
            u32 t = s0, Tt = s0;
            #pragma unroll
            for (int off = 1; off < 64; off <<= 1) {
                u32 x = __shfl_down(Tt, off, 64);
                Tt += (lane + off < 64) ? x : 0u;
            }
            u32 above = Tt - t;
            u32 S0 = s0 + above, S1 = s1 + above, S2 = s2 + above, S3 = s3 + above;
            u32 Sx[5] = { S0, S1, S2, S3, above };
            #pragma unroll
            for (int i2 = 0; i2 < 4; ++i2) {
                if ((int)Sx[i2] >= r && (int)Sx[i2+1] < r) {
                    *sh_prefix = pref | ((u32)(lane * 4 + i2) << (d * 8));
                    *sh_r = r - (int)Sx[i2+1];
                    *sh_neq = (int)(Sx[i2] - Sx[i2+1]);
                }
            }
        }
        __syncthreads();
    }
    pivot = *sh_prefix; needed = *sh_r; nge = (K - needed) + *sh_neq;
    __syncthreads();
}

// ---------------- Kernel 1: decode boxes + softmax ----------------
__global__ __launch_bounds__(256) void decode_softmax_kernel(
    const float* __restrict__ locs, const float* __restrict__ scores,
    const float* __restrict__ priors, float* __restrict__ dec,
    float* __restrict__ probs_t, int P, int C, int NC)
{
    __shared__ float tile[64 * 81];
    __shared__ float mrow[64], srow[64];
    const int b  = blockIdx.y;
    const int p0 = blockIdx.x * 64;
    const int tid = threadIdx.x;
    const int nrows = min(64, P - p0);
    const int n = nrows * C;

    const float* src = scores + ((size_t)b * P + p0) * C;
    for (int idx = tid; idx < n; idx += 256) tile[idx] = src[idx];

    if (tid < nrows) {
        int p = p0 + tid;
        float4 lc = ((const float4*)locs)[(size_t)b * P + p];
        float4 pr = ((const float4*)priors)[p];
        float cx = lc.x * pr.z / 10.0f + pr.x;
        float cy = lc.y * pr.w / 10.0f + pr.y;
        float w  = expf(lc.z / 5.0f) * pr.z;
        float h  = expf(lc.w / 5.0f) * pr.w;
        ((float4*)dec)[(size_t)b * P + p] =
            make_float4(cx - w * 0.5f, cy - h * 0.5f, cx + w * 0.5f, cy + h * 0.5f);
    }
    __syncthreads();

    if (tid < nrows) {
        const float* row = &tile[tid * C];
        float m = row[0];
        for (int cc = 1; cc < C; ++cc) m = fmaxf(m, row[cc]);
        float ss = 0.f;
        for (int cc = 0; cc < C; ++cc) ss += expf(row[cc] - m);
        mrow[tid] = m; srow[tid] = ss;
    }
    __syncthreads();

    for (int idx = tid; idx < 64 * NC; idx += 256) {
        int r  = idx & 63;
        int cc = idx >> 6;
        if (r < nrows) {
            float v = expf(tile[r * C + cc + 1] - mrow[r]) / srow[r];
            probs_t[((size_t)(b * NC + cc)) * P + p0 + r] = v;
        }
    }
}

// ---------------- Kernel 2a: per (class,image) exact top-400 selection ----------------
__global__ __launch_bounds__(512) void select_kernel(
    const float* __restrict__ probs_t, u64* __restrict__ cand512,
    int* __restrict__ cnt512, int P, int NC)
{
    const int c = blockIdx.x, b = blockIdx.y;
    const int tid = threadIdx.x;
    const int T = 512;

    __shared__ u32 skey[8736];
    __shared__ u32 hist[256];
    __shared__ u32 sh_prefix;
    __shared__ int sh_r, sh_neq, sh_cnt;

    const float* ps = probs_t + ((size_t)(b * NC + c)) * P;
    u64* outk = cand512 + (size_t)(b * NC + c) * 512;

    int P4 = P >> 2;
    for (int i = tid; i < P4; i += T) {
        float4 f4 = ((const float4*)ps)[i];
        skey[i*4+0] = f32_key(f4.x > MIN_SCORE ? f4.x : -1.0f);
        skey[i*4+1] = f32_key(f4.y > MIN_SCORE ? f4.y : -1.0f);
        skey[i*4+2] = f32_key(f4.z > MIN_SCORE ? f4.z : -1.0f);
        skey[i*4+3] = f32_key(f4.w > MIN_SCORE ? f4.w : -1.0f);
    }
    for (int i = (P4 << 2) + tid; i < P; i += T) {
        float f = ps[i];
        skey[i] = f32_key(f > MIN_SCORE ? f : -1.0f);
    }
    if (tid == 0) sh_cnt = 0;
    __syncthreads();

    u32 pivot; int needed, nge;
    radix_select32([&](int i, u32& k) { k = skey[i]; return true; },
                   P, WPRE, tid, T, hist, &sh_prefix, &sh_r, &sh_neq,
                   pivot, needed, nge);

    if (nge <= 512) {
        for (int i = tid; i < P; i += T) {
            u32 k = skey[i];
            if (k >= pivot) {
                int pos = atomicAdd(&sh_cnt, 1);
                outk[pos] = ((u64)k << 32) | (u64)(~(u32)i);
            }
        }
    } else {
        u32 pivot2; int needed2, nge2;
        radix_select32([&](int i, u32& k) {
                           if (skey[i] != pivot) return false;
                           k = ~(u32)i; return true;
                       },
                       P, needed, tid, T, hist, &sh_prefix, &sh_r, &sh_neq,
                       pivot2, needed2, nge2);
        for (int i = tid; i < P; i += T) {
            u32 k = skey[i];
            if (k > pivot || (k == pivot && (~(u32)i) >= pivot2)) {
                int pos = atomicAdd(&sh_cnt, 1);
                outk[pos] = ((u64)k << 32) | (u64)(~(u32)i);
            }
        }
    }
    __syncthreads();
    int cnt = sh_cnt;              // in [400, 512]
    if (tid >= cnt) outk[tid] = 0ull;
    if (tid == 0) cnt512[b * NC + c] = cnt;
}

// ---------------- Kernel 2b: sort + IoU matrix (registers) + hierarchical scan ----------------
__global__ __launch_bounds__(512) void nms_kernel(
    const float* __restrict__ dec, const u64* __restrict__ cand512,
    const int* __restrict__ cnt512,
    float* __restrict__ cand_sc, float* __restrict__ cand_bx,
    int P, int NC)
{
    const int c = blockIdx.x, b = blockIdx.y;
    const int tid = threadIdx.x;
    const int lane = tid & 63;
    const int wv = tid >> 6;

    __shared__ u64 cand[512];
    __shared__ float4 cbox[448];
    __shared__ float ara[448];
    __shared__ u64 validm[7], keepm[7], supB[7];

    const int cnt = cnt512[b * NC + c];
    u64 v = (tid < cnt) ? cand512[(size_t)(b * NC + c) * 512 + tid] : 0ull;

    // register bitonic sort 512 desc: shfl within wave, LDS for j>=64
    for (int k = 2; k <= 512; k <<= 1) {
        for (int j = k >> 1; j > 0; j >>= 1) {
            u64 p;
            if (j < 64) {
                p = __shfl_xor(v, j, 64);
            } else {
                __syncthreads();
                cand[tid] = v;
                __syncthreads();
                p = cand[tid ^ j];
            }
            bool takeMax = (((tid & k) == 0) == ((tid & j) == 0));
            v = takeMax ? (v > p ? v : p) : (v > p ? p : v);
        }
    }
    __syncthreads();

    // unpack rank-tid candidate into SoA; slots 400..447 zero-pad
    float4 mybox = make_float4(0.f, 0.f, 0.f, 0.f);
    float myval = -1.0f;
    if (tid < 448) {
        if (tid < WPRE) {
            myval = key_f32((u32)(v >> 32));
            int p = (int)(~(u32)v);
            mybox = ((const float4*)dec)[(size_t)b * P + p];
        }
        cbox[tid] = mybox;
        ara[tid] = (mybox.z - mybox.x) * (mybox.w - mybox.y);
        u64 mk = __ballot(myval > MIN_SCORE);
        if (lane == 0) validm[tid >> 6] = mk;
    }
    if (tid < 7) supB[tid] = 0ull;
    __syncthreads();

    // IoU bit-matrix: wave r owns row-block r. After tile (r,w), lane l holds
    // row (r*64+l)'s suppression word for column-block w in register rw[w].
    u64 rw[7];
    #pragma unroll
    for (int q = 0; q < 7; ++q) rw[q] = 0ull;
    if (wv < 7) {
        const int r = wv;
        const int nrows = (r == 6) ? (WPRE - 384) : 64;
        #pragma unroll
        for (int w = 0; w < 7; ++w) {
            if (w < r) continue;                 // wave-uniform skip
            int j = (w << 6) + lane;
            float4 bj = cbox[j];
            float aj = ara[j];
            u32 rlo = 0u, rhi = 0u;
            #pragma unroll 8
            for (int k2 = 0; k2 < nrows; ++k2) {
                int i = (r << 6) + k2;
                float4 bi = cbox[i];
                float ai = ara[i];
                float lx = fmaxf(bi.x, bj.x);
                float ly = fmaxf(bi.y, bj.y);
                float rx = fminf(bi.z, bj.z);
                float ry = fminf(bi.w, bj.w);
                float ww = fmaxf(rx - lx, 0.f);
                float hh = fmaxf(ry - ly, 0.f);
                float inter = ww * hh;
                float uniC = fmaxf((ai + aj) - inter, 1e-10f);
                bool pred = (double)inter > IOU_MID * (double)uniC;
                u64 vote = __ballot(pred);
                rlo = wr_lane((u32)vote, k2, rlo);
                rhi = wr_lane((u32)(vote >> 32), k2, rhi);
            }
            u64 myrow = ((u64)rhi << 32) | rlo;
            if (w == r) myrow &= ~(1ull << lane);    // diagonal
            rw[w] = myrow;
        }
    }
    __syncthreads();

    // Hierarchical scan: 7 sequential phases; phase w run by wave w alone.
    // Diagonal: fully-unrolled readlane scan (scalar dep chain, no LDS).
    // Cross-block: masked shfl OR-reduce of rw[wp] over active rows.
    #pragma unroll
    for (int w = 0; w < 7; ++w) {
        if (wv == w) {
            u64 avail = rfl64(validm[w] & ~supB[w]);
            u64 dw = rw[w];
            const int nt = (w == 6) ? (WPRE - 384) : 64;
            #pragma unroll
            for (int t = 0; t < nt; ++t) {
                u64 wt = rd_lane64(dw, t);
                if ((avail >> t) & 1ull) avail &= ~wt;
            }
            if (lane == 0) keepm[w] = avail;
            #pragma unroll
            for (int wp = w + 1; wp < 7; ++wp) {
                u64 cb = ((avail >> lane) & 1ull) ? rw[wp] : 0ull;
                #pragma unroll
                for (int off = 32; off > 0; off >>= 1) cb |= __shfl_xor(cb, off, 64);
                if (lane == 0) supB[wp] |= cb;
            }
        }
        __syncthreads();
    }

    if (tid < WPRE) {
        bool keep = (keepm[tid >> 6] >> (tid & 63)) & 1ull;
        cand_sc[((size_t)(b * NC + c)) * WPRE + tid] = keep ? myval : -1.0f;
        ((float4*)cand_bx)[((size_t)(b * NC + c)) * WPRE + tid] = mybox;
    }
}

// ---------------- Kernel 3a: per (image, class-group) exact top-200 ----------------
__global__ __launch_bounds__(512) void topkA_kernel(
    const float* __restrict__ cand_sc, u64* __restrict__ wsA,
    int NC, int TOPK, int GS, int NG)
{
    const int g = blockIdx.x, b = blockIdx.y;
    const int tid = threadIdx.x;
    const int T = 512;
    const int N = GS;                 // 3200
    const u32 fbase = (u32)(g * GS);  // global flat offset within image

    __shared__ u32 hist[256];
    __shared__ u32 sh_prefix;
    __shared__ int sh_r, sh_neq, sh_cnt;

    const float* s = cand_sc + (size_t)b * NC * WPRE + (size_t)g * GS;
    u64* outg = wsA + (size_t)(b * NG + g) * 256;

    if (tid == 0) sh_cnt = 0;
    __syncthreads();

    u32 pivot; int needed, nge;
    radix_select32([&](int i, u32& k) { k = f32_key(s[i]); return true; },
                   N, TOPK, tid, T, hist, &sh_prefix, &sh_r, &sh_neq,
                   pivot, needed, nge);

    if (nge <= 256) {
        for (int i = tid; i < N; i += T) {
            u32 k = f32_key(s[i]);
            if (k >= pivot) {
                int pos = atomicAdd(&sh_cnt, 1);
                outg[pos] = ((u64)k << 32) | (u64)(~(fbase + (u32)i));
            }
        }
    } else {
        u32 pivot2; int needed2, nge2;
        radix_select32([&](int i, u32& k) {
                           if (f32_key(s[i]) != pivot) return false;
                           k = ~(u32)i; return true;
                       },
                       N, needed, tid, T, hist, &sh_prefix, &sh_r, &sh_neq,
                       pivot2, needed2, nge2);
        for (int i = tid; i < N; i += T) {
            u32 k = f32_key(s[i]);
            if (k > pivot || (k == pivot && (~(u32)i) >= pivot2)) {
                int pos = atomicAdd(&sh_cnt, 1);
                outg[pos] = ((u64)k << 32) | (u64)(~(fbase + (u32)i));
            }
        }
    }
    __syncthreads();
    int cnt = sh_cnt;   // in [TOPK, 256]
    if (tid < 256 && tid >= cnt) outg[tid] = 0ull;
}

// ---------------- Kernel 3b: merge groups, exact top-200, emit ----------------
__global__ __launch_bounds__(256) void topkB_kernel(
    const u64* __restrict__ wsA, const float* __restrict__ cand_bx,
    float* __restrict__ out, int NC, int TOPK, int B, int NG)
{
    const int b = blockIdx.x;
    const int tid = threadIdx.x;
    const int T = 256;
    const int N = NG * 256;           // 2560

    __shared__ u64 keys[2560];
    __shared__ u32 hist[256];
    __shared__ u64 cand[256];
    __shared__ u32 sh_prefix;
    __shared__ int sh_r, sh_neq, sh_cnt;

    const u64* src = wsA + (size_t)b * N;
    for (int i = tid; i < N; i += T) keys[i] = src[i];
    if (tid == 0) sh_cnt = 0;
    __syncthreads();

    u32 pivot; int needed, nge;
    radix_select32([&](int i, u32& k) { k = (u32)(keys[i] >> 32); return true; },
                   N, TOPK, tid, T, hist, &sh_prefix, &sh_r, &sh_neq,
                   pivot, needed, nge);

    if (nge <= 256) {
        for (int i = tid; i < N; i += T) {
            u64 kk = keys[i];
            if ((u32)(kk >> 32) >= pivot) {
                int pos = atomicAdd(&sh_cnt, 1);
                cand[pos] = kk;
            }
        }
    } else {
        u32 pivot2; int needed2, nge2;
        radix_select32([&](int i, u32& k) {
                           u64 kk = keys[i];
                           if ((u32)(kk >> 32) != pivot) return false;
                           k = (u32)kk; return true;
                       },
                       N, needed, tid, T, hist, &sh_prefix, &sh_r, &sh_neq,
                       pivot2, needed2, nge2);
        for (int i = tid; i < N; i += T) {
            u64 kk = keys[i];
            u32 hi = (u32)(kk >> 32);
            if (hi > pivot || (hi == pivot && ((u32)kk) >= pivot2)) {
                int pos = atomicAdd(&sh_cnt, 1);
                cand[pos] = kk;
            }
        }
    }
    __syncthreads();
    int cnt = sh_cnt;
    u64 v = (tid < cnt) ? cand[tid] : 0ull;

    // register bitonic sort 256 desc (full u64 -> exact (score, flat) order)
    for (int k = 2; k <= 256; k <<= 1) {
        for (int j = k >> 1; j > 0; j >>= 1) {
            u64 p;
            if (j < 64) {
                p = __shfl_xor(v, j, 64);
            } else {
                __syncthreads();
                cand[tid] = v;
                __syncthreads();
                p = cand[tid ^ j];
            }
            bool takeMax = (((tid & k) == 0) == ((tid & j) == 0));
            v = takeMax ? (v > p ? v : p) : (v > p ? p : v);
        }
    }

    if (tid < TOPK) {
        float sc = key_f32((u32)(v >> 32));
        int flat = (int)(~(u32)v);
        int cls = flat / WPRE;
        float4 bx = ((const float4*)cand_bx)[(size_t)b * NC * WPRE + flat];
        float* ob = out + ((size_t)(b * TOPK + tid)) * 4;
        ob[0] = bx.x; ob[1] = bx.y; ob[2] = bx.z; ob[3] = bx.w;
        out[(size_t)B * TOPK * 4 + (size_t)b * TOPK + tid] = (float)(cls + 1);
        out[(size_t)B * TOPK * 5 + (size_t)b * TOPK + tid] = sc;
    }
}

extern "C" void kernel_launch(void* const* d_in, const int* in_sizes, int n_in,
                              void* d_out, int out_size, void* d_ws, size_t ws_size,
                              hipStream_t stream) {
    const float* locs   = (const float*)d_in[0];
    const float* scores = (const float*)d_in[1];
    const float* priors = (const float*)d_in[2];

    const int P  = in_sizes[2] / 4;          // 8732
    const int B  = in_sizes[0] / (4 * P);    // 8
    const int C  = in_sizes[1] / (B * P);    // 81
    const int NC = C - 1;                    // 80
    const int TOPK = out_size / (B * 6);     // 200
    const int NG = 10;                       // class groups per image
    const int GS = (NC * WPRE) / NG;         // 3200 entries per group

    float* ws      = (float*)d_ws;
    float* dec     = ws;                                    // B*P*4
    float* probs_t = dec + (size_t)B * P * 4;               // B*NC*P
    float* cand_sc = probs_t + (size_t)B * NC * P;          // B*NC*WPRE
    float* cand_bx = cand_sc + (size_t)B * NC * WPRE;       // B*NC*WPRE*4
    u64*   cand512 = (u64*)(cand_bx + (size_t)B * NC * WPRE * 4);  // B*NC*512 u64
    int*   cnt512  = (int*)(cand512 + (size_t)B * NC * 512);       // B*NC
    u64*   wsA     = cand512;   // stage-A keys reuse cand512 region (stream-ordered dead)

    dim3 g1((P + 63) / 64, B);
    decode_softmax_kernel<<<g1, 256, 0, stream>>>(locs, scores, priors, dec, probs_t, P, C, NC);

    dim3 g2(NC, B);
    select_kernel<<<g2, 512, 0, stream>>>(probs_t, cand512, cnt512, P, NC);
    nms_kernel<<<g2, 512, 0, stream>>>(dec, cand512, cnt512, cand_sc, cand_bx, P, NC);

    dim3 g3(NG, B);
    topkA_kernel<<<g3, 512, 0, stream>>>(cand_sc, wsA, NC, TOPK, GS, NG);
    topkB_kernel<<<dim3(B), 256, 0, stream>>>(wsA, cand_bx, (float*)d_out, NC, TOPK, B, NG);
}

// Round 7
// 164.989 us; speedup vs baseline: 1.7504x; 1.0968x over previous
//
#include <hip/hip_runtime.h>
#include <cstdint>

typedef unsigned long long u64;
typedef unsigned int u32;

#define WPRE 400
#define MIN_SCORE 0.01f
#define MAX_OVERLAP 0.45f

// Exact predicate: fdiv_rn(inter,uniC) > 0.45f  <=>  (double)inter > MID*(double)uniC
// MID = midpoint(0.45f, nextafterf(0.45f,+inf)) = 0x1.CCCCCDp-2 (exact double).
#define IOU_MID 0x1.CCCCCDp-2

__device__ __forceinline__ u32 f32_key(float f) {
    u32 u = __float_as_uint(f);
    return (f >= 0.0f) ? (u | 0x80000000u) : ~u;
}
__device__ __forceinline__ float key_f32(u32 k) {
    return __uint_as_float((k & 0x80000000u) ? (k ^ 0x80000000u) : ~k);
}

// Exact K-th selection over 32-bit keys (descending), 4 x 8-bit MSD radix.
// Ballot-grouped histogram; single-wave shfl suffix-scan for pivot bin.
template <typename KF>
__device__ void radix_select32(KF kf, int N, int K, int tid, int T,
                               u32* hist, u32* sh_prefix, int* sh_r, int* sh_neq,
                               u32& pivot, int& needed, int& nge)
{
    const int lane = tid & 63;
    if (tid == 0) { *sh_prefix = 0u; *sh_r = K; *sh_neq = 0; }
    __syncthreads();
    for (int d = 3; d >= 0; --d) {
        u32 pref = *sh_prefix;
        if (tid < 256) hist[tid] = 0u;
        __syncthreads();
        for (int i = tid; i < N; i += T) {
            u32 k = 0u;
            bool ok = kf(i, k);
            bool match = ok && ((d == 3) || (((k ^ pref) >> ((d + 1) * 8)) == 0u));
            u64 m = __ballot(match);
            if (m == 0ull) continue;            // uniform skip
            u32 dig = (k >> (d * 8)) & 255u;
            #pragma unroll
            for (int bb = 0; bb < 8; ++bb) {
                u64 bm = __ballot((int)((dig >> bb) & 1u));
                m &= ((dig >> bb) & 1u) ? bm : ~bm;
            }
            if (match) {
                u64 lower = m & ((1ull << lane) - 1ull);
                if (lower == 0ull) atomicAdd(&hist[dig], (u32)__builtin_popcountll(m));
            }
        }
        __syncthreads();
        if (tid < 64) {
            int r = *sh_r;
            u32 h0 = hist[lane*4+0], h1 = hist[lane*4+1];
            u32 h2 = hist[lane*4+2], h3 = hist[lane*4+3];
            u32 s3 = h3, s2 = h2 + s3, s1 = h1 + s2, s0 = h0 + s1;
            u32 t = s0, Tt = s0;
            #pragma unroll
            for (int off = 1; off < 64; off <<= 1) {
                u32 x = __shfl_down(Tt, off, 64);
                Tt += (lane + off < 64) ? x : 0u;
            }
            u32 above = Tt - t;
            u32 S0 = s0 + above, S1 = s1 + above, S2 = s2 + above, S3 = s3 + above;
            u32 Sx[5] = { S0, S1, S2, S3, above };
            #pragma unroll
            for (int i2 = 0; i2 < 4; ++i2) {
                if ((int)Sx[i2] >= r && (int)Sx[i2+1] < r) {
                    *sh_prefix = pref | ((u32)(lane * 4 + i2) << (d * 8));
                    *sh_r = r - (int)Sx[i2+1];
                    *sh_neq = (int)(Sx[i2] - Sx[i2+1]);
                }
            }
        }
        __syncthreads();
    }
    pivot = *sh_prefix; needed = *sh_r; nge = (K - needed) + *sh_neq;
    __syncthreads();
}

// ---------------- Kernel 1: decode boxes + softmax ----------------
__global__ __launch_bounds__(256) void decode_softmax_kernel(
    const float* __restrict__ locs, const float* __restrict__ scores,
    const float* __restrict__ priors, float* __restrict__ dec,
    float* __restrict__ probs_t, int P, int C, int NC)
{
    __shared__ float tile[64 * 81];
    __shared__ float mrow[64], srow[64];
    const int b  = blockIdx.y;
    const int p0 = blockIdx.x * 64;
    const int tid = threadIdx.x;
    const int nrows = min(64, P - p0);
    const int n = nrows * C;

    const float* src = scores + ((size_t)b * P + p0) * C;
    for (int idx = tid; idx < n; idx += 256) tile[idx] = src[idx];

    if (tid < nrows) {
        int p = p0 + tid;
        float4 lc = ((const float4*)locs)[(size_t)b * P + p];
        float4 pr = ((const float4*)priors)[p];
        float cx = lc.x * pr.z / 10.0f + pr.x;
        float cy = lc.y * pr.w / 10.0f + pr.y;
        float w  = expf(lc.z / 5.0f) * pr.z;
        float h  = expf(lc.w / 5.0f) * pr.w;
        ((float4*)dec)[(size_t)b * P + p] =
            make_float4(cx - w * 0.5f, cy - h * 0.5f, cx + w * 0.5f, cy + h * 0.5f);
    }
    __syncthreads();

    if (tid < nrows) {
        const float* row = &tile[tid * C];
        float m = row[0];
        for (int cc = 1; cc < C; ++cc) m = fmaxf(m, row[cc]);
        float ss = 0.f;
        for (int cc = 0; cc < C; ++cc) ss += expf(row[cc] - m);
        mrow[tid] = m; srow[tid] = ss;
    }
    __syncthreads();

    for (int idx = tid; idx < 64 * NC; idx += 256) {
        int r  = idx & 63;
        int cc = idx >> 6;
        if (r < nrows) {
            float v = expf(tile[r * C + cc + 1] - mrow[r]) / srow[r];
            probs_t[((size_t)(b * NC + cc)) * P + p0 + r] = v;
        }
    }
}

// ---------------- Kernel 2a: per (class,image) exact top-400 selection ----------------
__global__ __launch_bounds__(512) void select_kernel(
    const float* __restrict__ probs_t, u64* __restrict__ cand512,
    int* __restrict__ cnt512, int P, int NC)
{
    const int c = blockIdx.x, b = blockIdx.y;
    const int tid = threadIdx.x;
    const int T = 512;

    __shared__ u32 skey[8736];
    __shared__ u32 hist[256];
    __shared__ u32 sh_prefix;
    __shared__ int sh_r, sh_neq, sh_cnt;

    const float* ps = probs_t + ((size_t)(b * NC + c)) * P;
    u64* outk = cand512 + (size_t)(b * NC + c) * 512;

    int P4 = P >> 2;
    for (int i = tid; i < P4; i += T) {
        float4 f4 = ((const float4*)ps)[i];
        skey[i*4+0] = f32_key(f4.x > MIN_SCORE ? f4.x : -1.0f);
        skey[i*4+1] = f32_key(f4.y > MIN_SCORE ? f4.y : -1.0f);
        skey[i*4+2] = f32_key(f4.z > MIN_SCORE ? f4.z : -1.0f);
        skey[i*4+3] = f32_key(f4.w > MIN_SCORE ? f4.w : -1.0f);
    }
    for (int i = (P4 << 2) + tid; i < P; i += T) {
        float f = ps[i];
        skey[i] = f32_key(f > MIN_SCORE ? f : -1.0f);
    }
    if (tid == 0) sh_cnt = 0;
    __syncthreads();

    u32 pivot; int needed, nge;
    radix_select32([&](int i, u32& k) { k = skey[i]; return true; },
                   P, WPRE, tid, T, hist, &sh_prefix, &sh_r, &sh_neq,
                   pivot, needed, nge);

    if (nge <= 512) {
        for (int i = tid; i < P; i += T) {
            u32 k = skey[i];
            if (k >= pivot) {
                int pos = atomicAdd(&sh_cnt, 1);
                outk[pos] = ((u64)k << 32) | (u64)(~(u32)i);
            }
        }
    } else {
        u32 pivot2; int needed2, nge2;
        radix_select32([&](int i, u32& k) {
                           if (skey[i] != pivot) return false;
                           k = ~(u32)i; return true;
                       },
                       P, needed, tid, T, hist, &sh_prefix, &sh_r, &sh_neq,
                       pivot2, needed2, nge2);
        for (int i = tid; i < P; i += T) {
            u32 k = skey[i];
            if (k > pivot || (k == pivot && (~(u32)i) >= pivot2)) {
                int pos = atomicAdd(&sh_cnt, 1);
                outk[pos] = ((u64)k << 32) | (u64)(~(u32)i);
            }
        }
    }
    __syncthreads();
    int cnt = sh_cnt;              // in [400, 512]
    if (tid >= cnt) outk[tid] = 0ull;
    if (tid == 0) cnt512[b * NC + c] = cnt;
}

// ---------------- Kernel 2b: sort + column-word IoU matrix + 1-wave scan ----------------
__global__ __launch_bounds__(512) void nms_kernel(
    const float* __restrict__ dec, const u64* __restrict__ cand512,
    const int* __restrict__ cnt512,
    float* __restrict__ cand_sc, float* __restrict__ cand_bx,
    int P, int NC)
{
    const int c = blockIdx.x, b = blockIdx.y;
    const int tid = threadIdx.x;
    const int lane = tid & 63;
    const int wv = tid >> 6;

    __shared__ u64 cand[512];
    __shared__ float4 cbox[448];
    __shared__ float ara[448];
    __shared__ u64 inw[7 * 7 * 64];     // [w][r][lane]: column words (rows of block r vs col w*64+lane)
    __shared__ u64 validm[7], keepm[7];

    const int cnt = cnt512[b * NC + c];
    u64 v = (tid < cnt) ? cand512[(size_t)(b * NC + c) * 512 + tid] : 0ull;

    // register bitonic sort 512 desc: shfl within wave, LDS for j>=64
    for (int k = 2; k <= 512; k <<= 1) {
        for (int j = k >> 1; j > 0; j >>= 1) {
            u64 p;
            if (j < 64) {
                p = __shfl_xor(v, j, 64);
            } else {
                __syncthreads();
                cand[tid] = v;
                __syncthreads();
                p = cand[tid ^ j];
            }
            bool takeMax = (((tid & k) == 0) == ((tid & j) == 0));
            v = takeMax ? (v > p ? v : p) : (v > p ? p : v);
        }
    }
    __syncthreads();

    // unpack rank-tid candidate into SoA; slots 400..447 zero-pad
    float4 mybox = make_float4(0.f, 0.f, 0.f, 0.f);
    float myval = -1.0f;
    if (tid < 448) {
        if (tid < WPRE) {
            myval = key_f32((u32)(v >> 32));
            int p = (int)(~(u32)v);
            mybox = ((const float4*)dec)[(size_t)b * P + p];
        }
        cbox[tid] = mybox;
        ara[tid] = (mybox.z - mybox.x) * (mybox.w - mybox.y);
        u64 mk = __ballot(myval > MIN_SCORE);
        if (lane == 0) validm[tid >> 6] = mk;
    }
    __syncthreads();

    // Column-word IoU matrix: 28 upper-triangle tiles balanced over 8 waves.
    // Lane holds column box j = w*64+lane; accumulates its own column word
    // (bit k2 = "row i=r*64+k2 suppresses j") -- no ballot, no writelane.
    for (int tt = wv; tt < 28; tt += 8) {
        int r = 0, base = 0;
        while (tt - base >= 7 - r) { base += 7 - r; ++r; }
        int w = r + (tt - base);
        int j = (w << 6) + lane;
        float4 bj = cbox[j];
        float aj = ara[j];
        u64 cw = 0ull;
        const int i0 = r << 6;
        #pragma unroll 8
        for (int k2 = 0; k2 < 64; ++k2) {
            int i = i0 + k2;
            float4 bi = cbox[i];
            float ai = ara[i];
            float lx = fmaxf(bi.x, bj.x);
            float ly = fmaxf(bi.y, bj.y);
            float rx = fminf(bi.z, bj.z);
            float ry = fminf(bi.w, bj.w);
            float ww = fmaxf(rx - lx, 0.f);
            float hh = fmaxf(ry - ly, 0.f);
            float inter = ww * hh;
            float uniC = fmaxf((ai + aj) - inter, 1e-10f);
            u64 sup = (u64)((double)inter > IOU_MID * (double)uniC);
            cw |= sup << k2;
        }
        inw[(w * 7 + r) * 64 + lane] = cw;
    }
    __syncthreads();

    // Single-wave hierarchical scan, zero barriers inside.
    // keep[r] = ballot of survivors of block r (uniform u64, registers).
    if (wv == 0) {
        u64 keep[7];
        #pragma unroll
        for (int w2 = 0; w2 < 7; ++w2) {
            bool alive = ((validm[w2] >> lane) & 1ull) != 0;
            #pragma unroll
            for (int r = 0; r < w2; ++r) {
                u64 inr = inw[(w2 * 7 + r) * 64 + lane];
                alive = alive && ((inr & keep[r]) == 0ull);
            }
            u64 in_self = inw[(w2 * 7 + w2) * 64 + lane];
            u64 inmask = in_self & ((1ull << lane) - 1ull);   // only t < lane matter
            u64 mm = inmask;
            #pragma unroll
            for (int off = 32; off; off >>= 1) mm |= __shfl_xor(mm, off, 64);
            while (mm) {                        // iterate only suppressing rows
                int t = __builtin_ctzll(mm);
                mm &= mm - 1ull;
                u64 am = __ballot(alive);
                if ((am >> t) & 1ull)
                    alive = alive && (((inmask >> t) & 1ull) == 0ull);
            }
            u64 fin = __ballot(alive);
            keep[w2] = fin;
            if (lane == 0) keepm[w2] = fin;
        }
    }
    __syncthreads();

    if (tid < WPRE) {
        bool keep = (keepm[tid >> 6] >> (tid & 63)) & 1ull;
        cand_sc[((size_t)(b * NC + c)) * WPRE + tid] = keep ? myval : -1.0f;
        ((float4*)cand_bx)[((size_t)(b * NC + c)) * WPRE + tid] = mybox;
    }
}

// ---------------- Kernel 3a: per (image, class-group) exact top-200 ----------------
__global__ __launch_bounds__(512) void topkA_kernel(
    const float* __restrict__ cand_sc, u64* __restrict__ wsA,
    int NC, int TOPK, int GS, int NG)
{
    const int g = blockIdx.x, b = blockIdx.y;
    const int tid = threadIdx.x;
    const int T = 512;
    const int N = GS;                 // 3200
    const u32 fbase = (u32)(g * GS);

    __shared__ u32 hist[256];
    __shared__ u32 sh_prefix;
    __shared__ int sh_r, sh_neq, sh_cnt;

    const float* s = cand_sc + (size_t)b * NC * WPRE + (size_t)g * GS;
    u64* outg = wsA + (size_t)(b * NG + g) * 256;

    if (tid == 0) sh_cnt = 0;
    __syncthreads();

    u32 pivot; int needed, nge;
    radix_select32([&](int i, u32& k) { k = f32_key(s[i]); return true; },
                   N, TOPK, tid, T, hist, &sh_prefix, &sh_r, &sh_neq,
                   pivot, needed, nge);

    if (nge <= 256) {
        for (int i = tid; i < N; i += T) {
            u32 k = f32_key(s[i]);
            if (k >= pivot) {
                int pos = atomicAdd(&sh_cnt, 1);
                outg[pos] = ((u64)k << 32) | (u64)(~(fbase + (u32)i));
            }
        }
    } else {
        u32 pivot2; int needed2, nge2;
        radix_select32([&](int i, u32& k) {
                           if (f32_key(s[i]) != pivot) return false;
                           k = ~(u32)i; return true;
                       },
                       N, needed, tid, T, hist, &sh_prefix, &sh_r, &sh_neq,
                       pivot2, needed2, nge2);
        for (int i = tid; i < N; i += T) {
            u32 k = f32_key(s[i]);
            if (k > pivot || (k == pivot && (~(u32)i) >= pivot2)) {
                int pos = atomicAdd(&sh_cnt, 1);
                outg[pos] = ((u64)k << 32) | (u64)(~(fbase + (u32)i));
            }
        }
    }
    __syncthreads();
    int cnt = sh_cnt;   // in [TOPK, 256]
    if (tid < 256 && tid >= cnt) outg[tid] = 0ull;
}

// ---------------- Kernel 3b: merge groups, exact top-200, emit ----------------
__global__ __launch_bounds__(256) void topkB_kernel(
    const u64* __restrict__ wsA, const float* __restrict__ cand_bx,
    float* __restrict__ out, int NC, int TOPK, int B, int NG)
{
    const int b = blockIdx.x;
    const int tid = threadIdx.x;
    const int T = 256;
    const int N = NG * 256;           // 2560

    __shared__ u64 keys[2560];
    __shared__ u32 hist[256];
    __shared__ u64 cand[256];
    __shared__ u32 sh_prefix;
    __shared__ int sh_r, sh_neq, sh_cnt;

    const u64* src = wsA + (size_t)b * N;
    for (int i = tid; i < N; i += T) keys[i] = src[i];
    if (tid == 0) sh_cnt = 0;
    __syncthreads();

    u32 pivot; int needed, nge;
    radix_select32([&](int i, u32& k) { k = (u32)(keys[i] >> 32); return true; },
                   N, TOPK, tid, T, hist, &sh_prefix, &sh_r, &sh_neq,
                   pivot, needed, nge);

    if (nge <= 256) {
        for (int i = tid; i < N; i += T) {
            u64 kk = keys[i];
            if ((u32)(kk >> 32) >= pivot) {
                int pos = atomicAdd(&sh_cnt, 1);
                cand[pos] = kk;
            }
        }
    } else {
        u32 pivot2; int needed2, nge2;
        radix_select32([&](int i, u32& k) {
                           u64 kk = keys[i];
                           if ((u32)(kk >> 32) != pivot) return false;
                           k = (u32)kk; return true;
                       },
                       N, needed, tid, T, hist, &sh_prefix, &sh_r, &sh_neq,
                       pivot2, needed2, nge2);
        for (int i = tid; i < N; i += T) {
            u64 kk = keys[i];
            u32 hi = (u32)(kk >> 32);
            if (hi > pivot || (hi == pivot && ((u32)kk) >= pivot2)) {
                int pos = atomicAdd(&sh_cnt, 1);
                cand[pos] = kk;
            }
        }
    }
    __syncthreads();
    int cnt = sh_cnt;
    u64 v = (tid < cnt) ? cand[tid] : 0ull;

    // register bitonic sort 256 desc (full u64 -> exact (score, flat) order)
    for (int k = 2; k <= 256; k <<= 1) {
        for (int j = k >> 1; j > 0; j >>= 1) {
            u64 p;
            if (j < 64) {
                p = __shfl_xor(v, j, 64);
            } else {
                __syncthreads();
                cand[tid] = v;
                __syncthreads();
                p = cand[tid ^ j];
            }
            bool takeMax = (((tid & k) == 0) == ((tid & j) == 0));
            v = takeMax ? (v > p ? v : p) : (v > p ? p : v);
        }
    }

    if (tid < TOPK) {
        float sc = key_f32((u32)(v >> 32));
        int flat = (int)(~(u32)v);
        int cls = flat / WPRE;
        float4 bx = ((const float4*)cand_bx)[(size_t)b * NC * WPRE + flat];
        float* ob = out + ((size_t)(b * TOPK + tid)) * 4;
        ob[0] = bx.x; ob[1] = bx.y; ob[2] = bx.z; ob[3] = bx.w;
        out[(size_t)B * TOPK * 4 + (size_t)b * TOPK + tid] = (float)(cls + 1);
        out[(size_t)B * TOPK * 5 + (size_t)b * TOPK + tid] = sc;
    }
}

extern "C" void kernel_launch(void* const* d_in, const int* in_sizes, int n_in,
                              void* d_out, int out_size, void* d_ws, size_t ws_size,
                              hipStream_t stream) {
    const float* locs   = (const float*)d_in[0];
    const float* scores = (const float*)d_in[1];
    const float* priors = (const float*)d_in[2];

    const int P  = in_sizes[2] / 4;          // 8732
    const int B  = in_sizes[0] / (4 * P);    // 8
    const int C  = in_sizes[1] / (B * P);    // 81
    const int NC = C - 1;                    // 80
    const int TOPK = out_size / (B * 6);     // 200
    const int NG = 10;                       // class groups per image
    const int GS = (NC * WPRE) / NG;         // 3200 entries per group

    float* ws      = (float*)d_ws;
    float* dec     = ws;                                    // B*P*4
    float* probs_t = dec + (size_t)B * P * 4;               // B*NC*P
    float* cand_sc = probs_t + (size_t)B * NC * P;          // B*NC*WPRE
    float* cand_bx = cand_sc + (size_t)B * NC * WPRE;       // B*NC*WPRE*4
    u64*   cand512 = (u64*)(cand_bx + (size_t)B * NC * WPRE * 4);  // B*NC*512 u64
    int*   cnt512  = (int*)(cand512 + (size_t)B * NC * 512);       // B*NC
    u64*   wsA     = cand512;   // stage-A keys reuse cand512 region (stream-ordered dead)

    dim3 g1((P + 63) / 64, B);
    decode_softmax_kernel<<<g1, 256, 0, stream>>>(locs, scores, priors, dec, probs_t, P, C, NC);

    dim3 g2(NC, B);
    select_kernel<<<g2, 512, 0, stream>>>(probs_t, cand512, cnt512, P, NC);
    nms_kernel<<<g2, 512, 0, stream>>>(dec, cand512, cnt512, cand_sc, cand_bx, P, NC);

    dim3 g3(NG, B);
    topkA_kernel<<<g3, 512, 0, stream>>>(cand_sc, wsA, NC, TOPK, GS, NG);
    topkB_kernel<<<dim3(B), 256, 0, stream>>>(wsA, cand_bx, (float*)d_out, NC, TOPK, B, NG);
}